// Round 5
// baseline (271.466 us; speedup 1.0000x reference)
//
#include <hip/hip_runtime.h>

// MHA: B=4, S=1024, E=1024, H=16, D=64.
// cast f32->bf16 + mask bias -> fused QKV GEMM (256x256 tile, counted-vmcnt
// 4-phase pipeline, 32x32x16 MFMA, k-half staged dbuf LDS, V stored in
// PV-fragment order, XCD swizzle) -> flash attention (S^T, no running max,
// T14 reg-staged K/V + T5 setprio) -> output GEMM (128x128 single-buffer).
// R5: qkv untouched (R4 best: 41.6us, conflicts 7.1M->2.4M). attn gets the
// T14 async-STAGE split: K/V tile t+1 loaded to REGISTERS right after the
// mid-barrier (issue-early), ds_write at top of t+1 (write-late) -- the
// QK+softmax+PV phase covers the global-load latency; compiler's automatic
// vmcnt wait before the dependent ds_write is the only sync needed. LDS image
// and per-lane source addresses byte-identical to the old global_load_lds
// path. setprio(1) around QK/PV MFMA clusters (T5, attn-verified +4-7%).

typedef unsigned short u16;
typedef __bf16 bf16x8 __attribute__((ext_vector_type(8)));
typedef __bf16 bf16x2 __attribute__((ext_vector_type(2)));
typedef short s16x4 __attribute__((ext_vector_type(4)));
typedef float f32x4 __attribute__((ext_vector_type(4)));
typedef float f32x16 __attribute__((ext_vector_type(16)));

struct alignas(8) us4_t { u16 x, y, z, w; };

__device__ __forceinline__ u16 f2bf(float x) {
  unsigned int u = __builtin_bit_cast(unsigned int, x);
  unsigned int r = u + 0x7fffu + ((u >> 16) & 1u);
  return (u16)(r >> 16);
}

__device__ __forceinline__ unsigned int pack2bf(float a, float b) {
#if __has_builtin(__builtin_amdgcn_cvt_pk_bf16_f32)
  bf16x2 r = __builtin_amdgcn_cvt_pk_bf16_f32(a, b);
  return __builtin_bit_cast(unsigned int, r);
#else
  return (unsigned int)f2bf(a) | ((unsigned int)f2bf(b) << 16);
#endif
}

__device__ __forceinline__ f32x4 zero4() {
  f32x4 z; z[0] = 0.f; z[1] = 0.f; z[2] = 0.f; z[3] = 0.f; return z;
}

__device__ __forceinline__ void async_copy16(const void* g, void* l) {
  __builtin_amdgcn_global_load_lds(
      (__attribute__((address_space(1))) void*)(uintptr_t)g,
      (__attribute__((address_space(3))) void*)l, 16, 0, 0);
}

// Gate: wait until only the newest N vmem ops are outstanding, then barrier.
#define GATE(N)                                                         \
  do {                                                                  \
    asm volatile("s_waitcnt vmcnt(" #N ")\n\ts_barrier" ::: "memory");  \
    __builtin_amdgcn_sched_barrier(0);                                  \
  } while (0)

// ---------------- fused cast: 7 tensors + mask->additive bias (log2 domain) ----
__global__ void fused_cast(const float* __restrict__ q, const float* __restrict__ k,
                           const float* __restrict__ v, const float* __restrict__ wq,
                           const float* __restrict__ wk, const float* __restrict__ wv,
                           const float* __restrict__ wo, const int* __restrict__ mask,
                           u16* __restrict__ qo, u16* __restrict__ ko, u16* __restrict__ vo,
                           u16* __restrict__ wqo, u16* __restrict__ wko, u16* __restrict__ wvo,
                           u16* __restrict__ woo, float* __restrict__ biasf) {
  const int blk = blockIdx.x;
  if (blk >= 16384) {
    int i = (blk - 16384) * 256 + threadIdx.x;  // 0..4095
    biasf[i] = mask[i] ? 0.f : -1.4427e20f;
    return;
  }
  const float* src; u16* dst; int off;
  if (blk < 4096)       { src = q;  dst = qo;  off = blk; }
  else if (blk < 8192)  { src = k;  dst = ko;  off = blk - 4096; }
  else if (blk < 12288) { src = v;  dst = vo;  off = blk - 8192; }
  else if (blk < 13312) { src = wq; dst = wqo; off = blk - 12288; }
  else if (blk < 14336) { src = wk; dst = wko; off = blk - 13312; }
  else if (blk < 15360) { src = wv; dst = wvo; off = blk - 14336; }
  else                  { src = wo; dst = woo; off = blk - 15360; }
  const size_t i = (size_t)off * 256 + threadIdx.x;
  float4 f = ((const float4*)src)[i];
  unsigned int lo = pack2bf(f.x, f.y), hi = pack2bf(f.z, f.w);
  unsigned long long pk = (unsigned long long)lo | ((unsigned long long)hi << 32);
  ((unsigned long long*)dst)[i] = pk;
}

// 8 independent 32x32x16 MFMAs (2mf x 2nf x 2ks) with setprio wrap (T5).
template <int MLO>
__device__ __forceinline__ void mm8(f32x16 (&acc)[4][2], const bf16x8 (&af)[2][2],
                                    const bf16x8 (&bfr)[2][2]) {
  __builtin_amdgcn_s_setprio(1);
#pragma unroll
  for (int ks = 0; ks < 2; ++ks)
#pragma unroll
    for (int mf = 0; mf < 2; ++mf)
#pragma unroll
      for (int nf = 0; nf < 2; ++nf)
        acc[MLO + mf][nf] = __builtin_amdgcn_mfma_f32_32x32x16_bf16(
            af[mf][ks], bfr[nf][ks], acc[MLO + mf][nf], 0, 0, 0);
  __builtin_amdgcn_s_setprio(0);
}

// ---------------- qkv GEMM: 256x256 tile, counted-vmcnt 4-phase pipeline -----
// (unchanged from R4; see R4 notes. Residual 2.36M bank conflicts = 4 cy/read.)
__global__ __launch_bounds__(512, 2) void qkv_gemm256(
    const u16* __restrict__ Xq, const u16* __restrict__ Xk, const u16* __restrict__ Xv,
    const u16* __restrict__ Wq, const u16* __restrict__ Wk, const u16* __restrict__ Wv,
    const float* __restrict__ bq, const float* __restrict__ bk, const float* __restrict__ bv,
    u16* __restrict__ Qo, u16* __restrict__ Ko, u16* __restrict__ Vto) {
  __shared__ u16 lA[2][2][256 * 32];
  __shared__ u16 lB[2][2][256 * 32];

  const int tid = threadIdx.x;
  const int lane = tid & 63, w = tid >> 6;   // 8 waves
  const int wm = w >> 2, wn = w & 3;         // 2 x 4
  const int l32 = lane & 31, hi = lane >> 5;

  // XCD swizzle: 192 blocks, 24 per XCD (bijective).
  const int flat = blockIdx.x;
  const int xcd = flat & 7, t = flat >> 3;   // t 0..23
  const int g = xcd * 24 + t;                // 0..191
  const int mt = g >> 2, n = g & 3;          // mt 0..47
  const int z = mt >> 4, m = mt & 15;
  const u16* A = (z == 0) ? Xq : (z == 1) ? Xk : Xv;
  const u16* W = (z == 0) ? Wq : (z == 1) ? Wk : Wv;
  const float* bias = (z == 0) ? bq : (z == 1) ? bk : bv;
  u16* out = (z == 0) ? Qo : (z == 1) ? Ko : Vto;
  const bool trans = (z == 2);
  const int m0 = m * 256, n0 = n * 256;

  f32x16 acc[4][2];
#pragma unroll
  for (int i = 0; i < 4; ++i)
#pragma unroll
    for (int j = 0; j < 2; ++j)
#pragma unroll
      for (int e = 0; e < 16; ++e) acc[i][j][e] = 0.f;

  int offA[2], offB[2];
#pragma unroll
  for (int t2 = 0; t2 < 2; ++t2) {
    const int row = (t2 * 8 + w) * 16 + (lane >> 2);
    const int c2 = (lane & 3) ^ ((lane >> 3) & 3);
    offA[t2] = (m0 + row) * 1024 + c2 * 8;
    offB[t2] = (n0 + row) * 1024 + c2 * 8;
  }

  const u16* cA = &lA[0][0][0];
  const u16* cB = &lB[0][0][0];
  u16* nA = (u16*)&lA[1][0][0];
  u16* nB = (u16*)&lB[1][0][0];

  auto stA = [&](u16* dst, int h, int k0) {
#pragma unroll
    for (int t2 = 0; t2 < 2; ++t2)
      async_copy16(A + (offA[t2] + k0 + h * 32), dst + h * 8192 + (t2 * 8 + w) * 512);
  };
  auto stB = [&](u16* dst, int h, int k0) {
#pragma unroll
    for (int t2 = 0; t2 < 2; ++t2)
      async_copy16(W + (offB[t2] + k0 + h * 32), dst + h * 8192 + (t2 * 8 + w) * 512);
  };
  auto rd = [&](const u16* base, int h, int row, int ks) -> bf16x8 {
    const int pc = (ks * 2 + hi) ^ ((row >> 1) & 3);
    return *(const bf16x8*)&base[h * 8192 + row * 32 + pc * 8];
  };

  // Prologue: stage tile 0 in steady-state issue order {Ak0, Bk0, Ak1, Bk1}.
  stA((u16*)cA, 0, 0);
  stB((u16*)cB, 0, 0);
  stA((u16*)cA, 1, 0);
  stB((u16*)cB, 1, 0);

  bf16x8 af[2][2], bfr[2][2];
  for (int kt = 0; kt < 16; ++kt) {
    const bool st = (kt < 15);
    const int k1 = (kt + 1) * 64;

    // ---- phase 1: k-half 0, mf 0-1 ----
    GATE(4);  // {Ak0,Bk0}(kt) complete; {Ak1,Bk1}(kt) may be in flight
#pragma unroll
    for (int mf = 0; mf < 2; ++mf)
#pragma unroll
      for (int ks = 0; ks < 2; ++ks)
        af[mf][ks] = rd(cA, 0, wm * 128 + mf * 32 + l32, ks);
#pragma unroll
    for (int nf = 0; nf < 2; ++nf)
#pragma unroll
      for (int ks = 0; ks < 2; ++ks)
        bfr[nf][ks] = rd(cB, 0, wn * 64 + nf * 32 + l32, ks);
    if (st) stA(nA, 0, k1);
    mm8<0>(acc, af, bfr);

    // ---- phase 2: k-half 0, mf 2-3 (B frags reused in regs) ----
#pragma unroll
    for (int mf = 0; mf < 2; ++mf)
#pragma unroll
      for (int ks = 0; ks < 2; ++ks)
        af[mf][ks] = rd(cA, 0, wm * 128 + (2 + mf) * 32 + l32, ks);
    if (st) stB(nB, 0, k1);
    mm8<2>(acc, af, bfr);

    // ---- phase 3: k-half 1, mf 0-1 ----
    if (st) { GATE(4); } else { GATE(0); }  // {Ak1,Bk1}(kt) complete
#pragma unroll
    for (int mf = 0; mf < 2; ++mf)
#pragma unroll
      for (int ks = 0; ks < 2; ++ks)
        af[mf][ks] = rd(cA, 1, wm * 128 + mf * 32 + l32, ks);
#pragma unroll
    for (int nf = 0; nf < 2; ++nf)
#pragma unroll
      for (int ks = 0; ks < 2; ++ks)
        bfr[nf][ks] = rd(cB, 1, wn * 64 + nf * 32 + l32, ks);
    if (st) stA(nA, 1, k1);
    mm8<0>(acc, af, bfr);

    // ---- phase 4: k-half 1, mf 2-3 ----
#pragma unroll
    for (int mf = 0; mf < 2; ++mf)
#pragma unroll
      for (int ks = 0; ks < 2; ++ks)
        af[mf][ks] = rd(cA, 1, wm * 128 + (2 + mf) * 32 + l32, ks);
    if (st) stB(nB, 1, k1);
    mm8<2>(acc, af, bfr);

    // swap buffers
    const u16* tA = cA; cA = nA; nA = (u16*)tA;
    const u16* tB = cB; cB = nB; nB = (u16*)tB;
  }

  // ---- epilogue (32x32 C/D frag: col = l32, row = (reg&3)+8*(reg>>2)+4*hi) --
#pragma unroll
  for (int nf = 0; nf < 2; ++nf) {
    const int cg = n0 + wn * 64 + nf * 32 + l32;
    const float bj = bias[cg];
#pragma unroll
    for (int mf = 0; mf < 4; ++mf) {
      const int mbase = m0 + wm * 128 + mf * 32 + 4 * hi;
#pragma unroll
      for (int g2 = 0; g2 < 4; ++g2) {
        const int r0 = mbase + 8 * g2;
        if (!trans) {
#pragma unroll
          for (int rr = 0; rr < 4; ++rr)
            out[(size_t)(r0 + rr) * 1024 + cg] = f2bf(acc[mf][nf][g2 * 4 + rr] + bj);
        } else {
          // V store in PV-fragment order: Vt2[bh][s>>2][d][s&3]; r0 % 4 == 0.
          const int bh = ((r0 >> 10) << 4) + (cg >> 6);
          const int gq = (r0 & 1023) >> 2;
          const int d = cg & 63;
          union { us4_t s; unsigned int u[2]; } pk;
          pk.u[0] = pack2bf(acc[mf][nf][g2 * 4 + 0] + bj, acc[mf][nf][g2 * 4 + 1] + bj);
          pk.u[1] = pack2bf(acc[mf][nf][g2 * 4 + 2] + bj, acc[mf][nf][g2 * 4 + 3] + bj);
          *(us4_t*)&out[(size_t)bh * 65536 + gq * 256 + d * 4] = pk.s;
        }
      }
    }
  }
}

// ---------------- 128x128 GEMM core (single-buffer), used by out_gemm --------
// C/D frag: col = lane&31, row = (reg&3) + 8*(reg>>2) + 4*(lane>>5).
template <bool OUT_BF16, int NT>
__device__ __forceinline__ void gemm_core32(const u16* __restrict__ A,
                                            const u16* __restrict__ Bw,
                                            const float* __restrict__ bias,
                                            void* __restrict__ outp, bool trans,
                                            int m0, int n0) {
  __shared__ u16 lA[128 * 64];
  __shared__ u16 lB[NT * 64 * 64];
  const int tid = threadIdx.x;
  const int lane = tid & 63, w = tid >> 6;
  const int wm = w >> 1, wn = w & 1;
  const int l32 = lane & 31, hi = lane >> 5;
  const int rg = lane >> 3, cs = lane & 7;

  f32x16 acc[2][NT];
#pragma unroll
  for (int i = 0; i < 2; ++i)
#pragma unroll
    for (int j = 0; j < NT; ++j)
#pragma unroll
      for (int e = 0; e < 16; ++e) acc[i][j][e] = 0.f;

  for (int it = 0; it < 16; ++it) {
    const int k0 = it * 64;
#pragma unroll
    for (int t = 0; t < 4; ++t) {
      const int row = w * 32 + t * 8 + rg;
      const int c = cs ^ (row & 7);
      async_copy16(A + (size_t)(m0 + row) * 1024 + k0 + c * 8, &lA[(w * 32 + t * 8) * 64]);
    }
#pragma unroll
    for (int t = 0; t < NT * 2; ++t) {
      const int row = w * (NT * 16) + t * 8 + rg;
      const int c = cs ^ (row & 7);
      async_copy16(Bw + (size_t)(n0 + row) * 1024 + k0 + c * 8,
                   &lB[(w * (NT * 16) + t * 8) * 64]);
    }
    __syncthreads();
#pragma unroll
    for (int s = 0; s < 4; ++s) {
      bf16x8 af[2], bfr[NT];
#pragma unroll
      for (int i = 0; i < 2; ++i) {
        const int row = wm * 64 + i * 32 + l32;
        af[i] = *(const bf16x8*)&lA[row * 64 + (((s * 2 + hi) ^ (row & 7)) * 8)];
      }
#pragma unroll
      for (int j = 0; j < NT; ++j) {
        const int row = wn * (NT * 32) + j * 32 + l32;
        bfr[j] = *(const bf16x8*)&lB[row * 64 + (((s * 2 + hi) ^ (row & 7)) * 8)];
      }
#pragma unroll
      for (int i = 0; i < 2; ++i)
#pragma unroll
        for (int j = 0; j < NT; ++j)
          acc[i][j] = __builtin_amdgcn_mfma_f32_32x32x16_bf16(af[i], bfr[j], acc[i][j], 0, 0, 0);
    }
    __syncthreads();
  }

#pragma unroll
  for (int j = 0; j < NT; ++j) {
    const int cg = n0 + wn * (NT * 32) + j * 32 + l32;
    const float bj = bias[cg];
#pragma unroll
    for (int i = 0; i < 2; ++i) {
      const int mbase = m0 + wm * 64 + i * 32 + 4 * hi;
#pragma unroll
      for (int g = 0; g < 4; ++g) {
        const int r0 = mbase + 8 * g;
        if (!trans) {
          if (OUT_BF16) {
            u16* o = (u16*)outp;
#pragma unroll
            for (int rr = 0; rr < 4; ++rr)
              o[(size_t)(r0 + rr) * 1024 + cg] = f2bf(acc[i][j][g * 4 + rr] + bj);
          } else {
            float* o = (float*)outp;
#pragma unroll
            for (int rr = 0; rr < 4; ++rr)
              o[(size_t)(r0 + rr) * 1024 + cg] = acc[i][j][g * 4 + rr] + bj;
          }
        } else {
          u16* o = (u16*)outp;
          const int bh = ((r0 >> 10) << 4) + (cg >> 6);
          const int g2 = (r0 & 1023) >> 2;
          const int d  = cg & 63;
          union { us4_t s; unsigned int u[2]; } pk;
          pk.u[0] = pack2bf(acc[i][j][g * 4 + 0] + bj, acc[i][j][g * 4 + 1] + bj);
          pk.u[1] = pack2bf(acc[i][j][g * 4 + 2] + bj, acc[i][j][g * 4 + 3] + bj);
          *(us4_t*)&o[(size_t)bh * 65536 + g2 * 256 + d * 4] = pk.s;
        }
      }
    }
  }
}

// out: grid 512 flat; xcd owns 4 m-bands of 16 n-blocks each.
__global__ __launch_bounds__(256, 3) void out_gemm(
    const u16* __restrict__ A, const u16* __restrict__ W,
    const float* __restrict__ bias, float* __restrict__ out) {
  const int flat = blockIdx.x;
  const int xcd = flat & 7, t = flat >> 3;
  const int n = t & 15, m = xcd * 4 + (t >> 4);
  gemm_core32<false, 1>(A, W, bias, out, false, m * 128, n * 64);
}

// ---------------- flash attention, S^T orientation, no running max ------------
// R5: T14 reg-staged K/V (issue after mid-barrier, ds_write at next iter top)
// + T5 setprio around MFMA clusters. LDS image identical to the gll version.
__global__ __launch_bounds__(256, 4) void attn_kernel(
    const u16* __restrict__ Qb, const u16* __restrict__ Kb, const u16* __restrict__ Vtb,
    const float* __restrict__ biasf, u16* __restrict__ Ob) {
  __shared__ u16 lK[128 * 64];
  __shared__ u16 lV[64 * 128];  // Vt2 slab, identity layout
  u16* lQ = lV;                 // prologue-only alias

  const int tid = threadIdx.x;
  const int lane = tid & 63, w = tid >> 6;
  const int quad = lane >> 4, l16 = lane & 15;
  const int rg = lane >> 3, cs = lane & 7;

  const int flat = blockIdx.x;
  const int xcd = flat & 7, r = flat >> 3;
  const int bh = xcd * 8 + (r & 7), qt = r >> 3;
  const int b = bh >> 4;
  const size_t qkBase = (size_t)b * 1048576 + (size_t)(bh & 15) * 64;
  const size_t vBase = (size_t)bh * 65536;
  const float C = 0.0450842200277982f;  // (1/sqrt(E)) * log2(e)
  const float* bp = biasf + b * 1024 + quad * 4;

#pragma unroll
  for (int t = 0; t < 2; ++t) {
    const int row = w * 16 + t * 8 + rg;
    const int c = cs ^ (row & 7);
    async_copy16(Qb + qkBase + (size_t)(qt * 64 + row) * 1024 + c * 8,
                 &lQ[(w * 16 + t * 8) * 64]);
  }
  __syncthreads();

  bf16x8 qf[2];
#pragma unroll
  for (int kk = 0; kk < 2; ++kk) {
    const int row = w * 16 + l16;
    qf[kk] = *(const bf16x8*)&lQ[row * 64 + (((kk * 4 + quad) ^ (row & 7)) * 8)];
  }
  __syncthreads();  // protect lQ before lV ds_write overwrites it

  // T14 staging state: per-thread source offsets (same per-lane addresses the
  // old global_load_lds produced), K/V tile in registers.
  const u16* Kp = Qb == nullptr ? nullptr : Kb + qkBase;  // keep simple
  const u16* Vp = Vtb + vBase;
  int kro[4];
#pragma unroll
  for (int t = 0; t < 4; ++t) {
    const int row = w * 32 + t * 8 + rg;
    const int c = cs ^ (row & 7);
    kro[t] = row * 1024 + c * 8;
  }
  const int vo = w * 2048 + lane * 8;

  float4 kreg[4], vreg[4];
#pragma unroll
  for (int t = 0; t < 4; ++t) kreg[t] = *(const float4*)&Kp[kro[t]];
#pragma unroll
  for (int t = 0; t < 4; ++t) vreg[t] = *(const float4*)&Vp[vo + t * 512];

  float lsum = 0.f;
  f32x4 oacc[4];
#pragma unroll
  for (int dt = 0; dt < 4; ++dt) oacc[dt] = zero4();

  for (int it = 0; it < 8; ++it) {
    const int k0 = it * 128;
    // write-late: publish staged tile (compiler inserts vmcnt waits on regs)
#pragma unroll
    for (int t = 0; t < 4; ++t)
      *(float4*)&lK[(w * 32 + t * 8) * 64 + lane * 8] = kreg[t];
#pragma unroll
    for (int t = 0; t < 4; ++t)
      *(float4*)&lV[(w * 4 + t) * 512 + lane * 8] = vreg[t];
    __syncthreads();
    // issue-early: next tile's loads, covered by this iteration's compute
    if (it < 7) {
      const int kn = (it + 1) * 128;
#pragma unroll
      for (int t = 0; t < 4; ++t)
        kreg[t] = *(const float4*)&Kp[(size_t)kn * 1024 + kro[t]];
#pragma unroll
      for (int t = 0; t < 4; ++t)
        vreg[t] = *(const float4*)&Vp[(size_t)(it + 1) * 8192 + vo + t * 512];
    }

    f32x4 sacc[8];
#pragma unroll
    for (int n = 0; n < 8; ++n) sacc[n] = zero4();
    __builtin_amdgcn_s_setprio(1);
#pragma unroll
    for (int kk = 0; kk < 2; ++kk) {
#pragma unroll
      for (int n = 0; n < 8; ++n) {
        const int row = n * 16 + l16;
        bf16x8 kf = *(const bf16x8*)&lK[row * 64 + (((kk * 4 + quad) ^ (row & 7)) * 8)];
        sacc[n] = __builtin_amdgcn_mfma_f32_16x16x32_bf16(kf, qf[kk], sacc[n], 0, 0, 0);
      }
    }
    __builtin_amdgcn_s_setprio(0);

    f32x4 sum4 = zero4();
#pragma unroll
    for (int n = 0; n < 8; ++n) {
      const float4 vb = *(const float4*)&bp[k0 + n * 16];
      sacc[n][0] = __builtin_amdgcn_exp2f(fmaf(sacc[n][0], C, vb.x));
      sacc[n][1] = __builtin_amdgcn_exp2f(fmaf(sacc[n][1], C, vb.y));
      sacc[n][2] = __builtin_amdgcn_exp2f(fmaf(sacc[n][2], C, vb.z));
      sacc[n][3] = __builtin_amdgcn_exp2f(fmaf(sacc[n][3], C, vb.w));
      sum4[0] += sacc[n][0]; sum4[1] += sacc[n][1];
      sum4[2] += sacc[n][2]; sum4[3] += sacc[n][3];
    }
    float rs = (sum4[0] + sum4[1]) + (sum4[2] + sum4[3]);
    rs += __shfl_xor(rs, 16);
    rs += __shfl_xor(rs, 32);
    lsum += rs;

    s16x4 pf[8];
#pragma unroll
    for (int n = 0; n < 8; ++n) {
      union { s16x4 v; unsigned int u[2]; } pu;
      pu.u[0] = pack2bf(sacc[n][0], sacc[n][1]);
      pu.u[1] = pack2bf(sacc[n][2], sacc[n][3]);
      pf[n] = pu.v;
    }

    __builtin_amdgcn_s_setprio(1);
#pragma unroll
    for (int dt = 0; dt < 4; ++dt) {
      const int dbase = (dt * 16 + l16) * 4;
#pragma unroll
      for (int ks = 0; ks < 8; ++ks) {
        s16x4 vf = *(const s16x4*)&lV[(ks * 4 + quad) * 256 + dbase];
        oacc[dt] = __builtin_amdgcn_mfma_f32_16x16x16bf16_1k(vf, pf[ks], oacc[dt], 0, 0, 0);
      }
    }
    __builtin_amdgcn_s_setprio(0);
    __syncthreads();
  }

  const float inv = 1.f / lsum;
  const int qg = qt * 64 + w * 16 + l16;
#pragma unroll
  for (int dt = 0; dt < 4; ++dt) {
    union { us4_t s; unsigned int u[2]; } pk;
    pk.u[0] = pack2bf(oacc[dt][0] * inv, oacc[dt][1] * inv);
    pk.u[1] = pack2bf(oacc[dt][2] * inv, oacc[dt][3] * inv);
    *(us4_t*)&Ob[qkBase + (size_t)qg * 1024 + dt * 16 + quad * 4] = pk.s;
  }
}

extern "C" void kernel_launch(void* const* d_in, const int* in_sizes, int n_in,
                              void* d_out, int out_size, void* d_ws, size_t ws_size,
                              hipStream_t stream) {
  const float* value  = (const float*)d_in[0];
  const float* key_in = (const float*)d_in[1];
  const float* query  = (const float*)d_in[2];
  const int*   mask   = (const int*)d_in[3];
  const float* Wq = (const float*)d_in[4];
  const float* bq = (const float*)d_in[5];
  const float* Wk = (const float*)d_in[6];
  const float* bk = (const float*)d_in[7];
  const float* Wv = (const float*)d_in[8];
  const float* bv = (const float*)d_in[9];
  const float* Wo = (const float*)d_in[10];
  const float* bo = (const float*)d_in[11];

  u16* ws = (u16*)d_ws;
  u16* q_bf  = ws;              // 4096x1024
  u16* k_bf  = ws + 4194304;
  u16* v_bf  = ws + 8388608;
  u16* wq_bf = ws + 12582912;   // 1024x1024 each
  u16* wk_bf = ws + 13631488;
  u16* wv_bf = ws + 14680064;
  u16* wo_bf = ws + 15728640;
  u16* Qbuf  = ws + 16777216;   // (b,s,h*64+d)
  u16* Kbuf  = ws + 20971520;
  u16* Vtbuf = ws + 25165824;   // Vt2[bh][s>>2][d][s&3]
  u16* attnb = ws + 29360128;   // (b,s,h*64+d)
  float* biasf = (float*)d_out; // consumed by attn, then overwritten by out_gemm

  fused_cast<<<16400, 256, 0, stream>>>(query, key_in, value, Wq, Wk, Wv, Wo, mask,
                                        q_bf, k_bf, v_bf, wq_bf, wk_bf, wv_bf, wo_bf,
                                        biasf);
  qkv_gemm256<<<dim3(192), 512, 0, stream>>>(q_bf, k_bf, v_bf, wq_bf, wk_bf, wv_bf,
                                             bq, bk, bv, Qbuf, Kbuf, Vtbuf);
  attn_kernel<<<dim3(1024), 256, 0, stream>>>(Qbuf, Kbuf, Vtbuf, biasf, attnb);
  out_gemm<<<dim3(512), 256, 0, stream>>>(attnb, wo_bf, bo, (float*)d_out);
}

// Round 6
// 209.680 us; speedup vs baseline: 1.2947x; 1.2947x over previous
//
#include <hip/hip_runtime.h>

// MHA: B=4, S=1024, E=1024, H=16, D=64.
// cast f32->bf16 + mask bias -> fused QKV GEMM (256x256 tile, counted-vmcnt
// 4-phase pipeline, 32x32x16 MFMA, k-half staged dbuf LDS, V stored in
// PV-fragment order, XCD swizzle) -> flash attention (S^T, no running max,
// global_load_lds staging + T5 setprio) -> output GEMM (128x128, NT=2).
// R6: R5's reg-staged attn SPILLED (WRITE_SIZE 8->233MB = scratch traffic);
// revert attn to R4's global_load_lds staging verbatim, keep only the T5
// setprio around MFMA clusters (attn-verified +4-7%, zero register cost).
// out_gemm: NT=1 -> NT=2 (128x128 tile, 256 blocks, same proven core as R0
// qkv) -- doubles B-panel reuse, halves staging traffic per output.
// qkv unchanged from R4.

typedef unsigned short u16;
typedef __bf16 bf16x8 __attribute__((ext_vector_type(8)));
typedef __bf16 bf16x2 __attribute__((ext_vector_type(2)));
typedef short s16x4 __attribute__((ext_vector_type(4)));
typedef float f32x4 __attribute__((ext_vector_type(4)));
typedef float f32x16 __attribute__((ext_vector_type(16)));

struct alignas(8) us4_t { u16 x, y, z, w; };

__device__ __forceinline__ u16 f2bf(float x) {
  unsigned int u = __builtin_bit_cast(unsigned int, x);
  unsigned int r = u + 0x7fffu + ((u >> 16) & 1u);
  return (u16)(r >> 16);
}

__device__ __forceinline__ unsigned int pack2bf(float a, float b) {
#if __has_builtin(__builtin_amdgcn_cvt_pk_bf16_f32)
  bf16x2 r = __builtin_amdgcn_cvt_pk_bf16_f32(a, b);
  return __builtin_bit_cast(unsigned int, r);
#else
  return (unsigned int)f2bf(a) | ((unsigned int)f2bf(b) << 16);
#endif
}

__device__ __forceinline__ f32x4 zero4() {
  f32x4 z; z[0] = 0.f; z[1] = 0.f; z[2] = 0.f; z[3] = 0.f; return z;
}

__device__ __forceinline__ void async_copy16(const void* g, void* l) {
  __builtin_amdgcn_global_load_lds(
      (__attribute__((address_space(1))) void*)(uintptr_t)g,
      (__attribute__((address_space(3))) void*)l, 16, 0, 0);
}

// Gate: wait until only the newest N vmem ops are outstanding, then barrier.
#define GATE(N)                                                         \
  do {                                                                  \
    asm volatile("s_waitcnt vmcnt(" #N ")\n\ts_barrier" ::: "memory");  \
    __builtin_amdgcn_sched_barrier(0);                                  \
  } while (0)

// ---------------- fused cast: 7 tensors + mask->additive bias (log2 domain) ----
__global__ void fused_cast(const float* __restrict__ q, const float* __restrict__ k,
                           const float* __restrict__ v, const float* __restrict__ wq,
                           const float* __restrict__ wk, const float* __restrict__ wv,
                           const float* __restrict__ wo, const int* __restrict__ mask,
                           u16* __restrict__ qo, u16* __restrict__ ko, u16* __restrict__ vo,
                           u16* __restrict__ wqo, u16* __restrict__ wko, u16* __restrict__ wvo,
                           u16* __restrict__ woo, float* __restrict__ biasf) {
  const int blk = blockIdx.x;
  if (blk >= 16384) {
    int i = (blk - 16384) * 256 + threadIdx.x;  // 0..4095
    biasf[i] = mask[i] ? 0.f : -1.4427e20f;
    return;
  }
  const float* src; u16* dst; int off;
  if (blk < 4096)       { src = q;  dst = qo;  off = blk; }
  else if (blk < 8192)  { src = k;  dst = ko;  off = blk - 4096; }
  else if (blk < 12288) { src = v;  dst = vo;  off = blk - 8192; }
  else if (blk < 13312) { src = wq; dst = wqo; off = blk - 12288; }
  else if (blk < 14336) { src = wk; dst = wko; off = blk - 13312; }
  else if (blk < 15360) { src = wv; dst = wvo; off = blk - 14336; }
  else                  { src = wo; dst = woo; off = blk - 15360; }
  const size_t i = (size_t)off * 256 + threadIdx.x;
  float4 f = ((const float4*)src)[i];
  unsigned int lo = pack2bf(f.x, f.y), hi = pack2bf(f.z, f.w);
  unsigned long long pk = (unsigned long long)lo | ((unsigned long long)hi << 32);
  ((unsigned long long*)dst)[i] = pk;
}

// 8 independent 32x32x16 MFMAs (2mf x 2nf x 2ks) with setprio wrap (T5).
template <int MLO>
__device__ __forceinline__ void mm8(f32x16 (&acc)[4][2], const bf16x8 (&af)[2][2],
                                    const bf16x8 (&bfr)[2][2]) {
  __builtin_amdgcn_s_setprio(1);
#pragma unroll
  for (int ks = 0; ks < 2; ++ks)
#pragma unroll
    for (int mf = 0; mf < 2; ++mf)
#pragma unroll
      for (int nf = 0; nf < 2; ++nf)
        acc[MLO + mf][nf] = __builtin_amdgcn_mfma_f32_32x32x16_bf16(
            af[mf][ks], bfr[nf][ks], acc[MLO + mf][nf], 0, 0, 0);
  __builtin_amdgcn_s_setprio(0);
}

// ---------------- qkv GEMM: 256x256 tile, counted-vmcnt 4-phase pipeline -----
// (unchanged from R4; see R4 notes. Residual 2.36M bank conflicts = 4 cy/read.)
__global__ __launch_bounds__(512, 2) void qkv_gemm256(
    const u16* __restrict__ Xq, const u16* __restrict__ Xk, const u16* __restrict__ Xv,
    const u16* __restrict__ Wq, const u16* __restrict__ Wk, const u16* __restrict__ Wv,
    const float* __restrict__ bq, const float* __restrict__ bk, const float* __restrict__ bv,
    u16* __restrict__ Qo, u16* __restrict__ Ko, u16* __restrict__ Vto) {
  __shared__ u16 lA[2][2][256 * 32];
  __shared__ u16 lB[2][2][256 * 32];

  const int tid = threadIdx.x;
  const int lane = tid & 63, w = tid >> 6;   // 8 waves
  const int wm = w >> 2, wn = w & 3;         // 2 x 4
  const int l32 = lane & 31, hi = lane >> 5;

  // XCD swizzle: 192 blocks, 24 per XCD (bijective).
  const int flat = blockIdx.x;
  const int xcd = flat & 7, t = flat >> 3;   // t 0..23
  const int g = xcd * 24 + t;                // 0..191
  const int mt = g >> 2, n = g & 3;          // mt 0..47
  const int z = mt >> 4, m = mt & 15;
  const u16* A = (z == 0) ? Xq : (z == 1) ? Xk : Xv;
  const u16* W = (z == 0) ? Wq : (z == 1) ? Wk : Wv;
  const float* bias = (z == 0) ? bq : (z == 1) ? bk : bv;
  u16* out = (z == 0) ? Qo : (z == 1) ? Ko : Vto;
  const bool trans = (z == 2);
  const int m0 = m * 256, n0 = n * 256;

  f32x16 acc[4][2];
#pragma unroll
  for (int i = 0; i < 4; ++i)
#pragma unroll
    for (int j = 0; j < 2; ++j)
#pragma unroll
      for (int e = 0; e < 16; ++e) acc[i][j][e] = 0.f;

  int offA[2], offB[2];
#pragma unroll
  for (int t2 = 0; t2 < 2; ++t2) {
    const int row = (t2 * 8 + w) * 16 + (lane >> 2);
    const int c2 = (lane & 3) ^ ((lane >> 3) & 3);
    offA[t2] = (m0 + row) * 1024 + c2 * 8;
    offB[t2] = (n0 + row) * 1024 + c2 * 8;
  }

  const u16* cA = &lA[0][0][0];
  const u16* cB = &lB[0][0][0];
  u16* nA = (u16*)&lA[1][0][0];
  u16* nB = (u16*)&lB[1][0][0];

  auto stA = [&](u16* dst, int h, int k0) {
#pragma unroll
    for (int t2 = 0; t2 < 2; ++t2)
      async_copy16(A + (offA[t2] + k0 + h * 32), dst + h * 8192 + (t2 * 8 + w) * 512);
  };
  auto stB = [&](u16* dst, int h, int k0) {
#pragma unroll
    for (int t2 = 0; t2 < 2; ++t2)
      async_copy16(W + (offB[t2] + k0 + h * 32), dst + h * 8192 + (t2 * 8 + w) * 512);
  };
  auto rd = [&](const u16* base, int h, int row, int ks) -> bf16x8 {
    const int pc = (ks * 2 + hi) ^ ((row >> 1) & 3);
    return *(const bf16x8*)&base[h * 8192 + row * 32 + pc * 8];
  };

  // Prologue: stage tile 0 in steady-state issue order {Ak0, Bk0, Ak1, Bk1}.
  stA((u16*)cA, 0, 0);
  stB((u16*)cB, 0, 0);
  stA((u16*)cA, 1, 0);
  stB((u16*)cB, 1, 0);

  bf16x8 af[2][2], bfr[2][2];
  for (int kt = 0; kt < 16; ++kt) {
    const bool st = (kt < 15);
    const int k1 = (kt + 1) * 64;

    // ---- phase 1: k-half 0, mf 0-1 ----
    GATE(4);  // {Ak0,Bk0}(kt) complete; {Ak1,Bk1}(kt) may be in flight
#pragma unroll
    for (int mf = 0; mf < 2; ++mf)
#pragma unroll
      for (int ks = 0; ks < 2; ++ks)
        af[mf][ks] = rd(cA, 0, wm * 128 + mf * 32 + l32, ks);
#pragma unroll
    for (int nf = 0; nf < 2; ++nf)
#pragma unroll
      for (int ks = 0; ks < 2; ++ks)
        bfr[nf][ks] = rd(cB, 0, wn * 64 + nf * 32 + l32, ks);
    if (st) stA(nA, 0, k1);
    mm8<0>(acc, af, bfr);

    // ---- phase 2: k-half 0, mf 2-3 (B frags reused in regs) ----
#pragma unroll
    for (int mf = 0; mf < 2; ++mf)
#pragma unroll
      for (int ks = 0; ks < 2; ++ks)
        af[mf][ks] = rd(cA, 0, wm * 128 + (2 + mf) * 32 + l32, ks);
    if (st) stB(nB, 0, k1);
    mm8<2>(acc, af, bfr);

    // ---- phase 3: k-half 1, mf 0-1 ----
    if (st) { GATE(4); } else { GATE(0); }  // {Ak1,Bk1}(kt) complete
#pragma unroll
    for (int mf = 0; mf < 2; ++mf)
#pragma unroll
      for (int ks = 0; ks < 2; ++ks)
        af[mf][ks] = rd(cA, 1, wm * 128 + mf * 32 + l32, ks);
#pragma unroll
    for (int nf = 0; nf < 2; ++nf)
#pragma unroll
      for (int ks = 0; ks < 2; ++ks)
        bfr[nf][ks] = rd(cB, 1, wn * 64 + nf * 32 + l32, ks);
    if (st) stA(nA, 1, k1);
    mm8<0>(acc, af, bfr);

    // ---- phase 4: k-half 1, mf 2-3 ----
#pragma unroll
    for (int mf = 0; mf < 2; ++mf)
#pragma unroll
      for (int ks = 0; ks < 2; ++ks)
        af[mf][ks] = rd(cA, 1, wm * 128 + (2 + mf) * 32 + l32, ks);
    if (st) stB(nB, 1, k1);
    mm8<2>(acc, af, bfr);

    // swap buffers
    const u16* tA = cA; cA = nA; nA = (u16*)tA;
    const u16* tB = cB; cB = nB; nB = (u16*)tB;
  }

  // ---- epilogue (32x32 C/D frag: col = l32, row = (reg&3)+8*(reg>>2)+4*hi) --
#pragma unroll
  for (int nf = 0; nf < 2; ++nf) {
    const int cg = n0 + wn * 64 + nf * 32 + l32;
    const float bj = bias[cg];
#pragma unroll
    for (int mf = 0; mf < 4; ++mf) {
      const int mbase = m0 + wm * 128 + mf * 32 + 4 * hi;
#pragma unroll
      for (int g2 = 0; g2 < 4; ++g2) {
        const int r0 = mbase + 8 * g2;
        if (!trans) {
#pragma unroll
          for (int rr = 0; rr < 4; ++rr)
            out[(size_t)(r0 + rr) * 1024 + cg] = f2bf(acc[mf][nf][g2 * 4 + rr] + bj);
        } else {
          // V store in PV-fragment order: Vt2[bh][s>>2][d][s&3]; r0 % 4 == 0.
          const int bh = ((r0 >> 10) << 4) + (cg >> 6);
          const int gq = (r0 & 1023) >> 2;
          const int d = cg & 63;
          union { us4_t s; unsigned int u[2]; } pk;
          pk.u[0] = pack2bf(acc[mf][nf][g2 * 4 + 0] + bj, acc[mf][nf][g2 * 4 + 1] + bj);
          pk.u[1] = pack2bf(acc[mf][nf][g2 * 4 + 2] + bj, acc[mf][nf][g2 * 4 + 3] + bj);
          *(us4_t*)&out[(size_t)bh * 65536 + gq * 256 + d * 4] = pk.s;
        }
      }
    }
  }
}

// ---------------- 128-row GEMM core (single-buffer), used by out_gemm --------
// C/D frag: col = lane&31, row = (reg&3) + 8*(reg>>2) + 4*(lane>>5).
template <bool OUT_BF16, int NT>
__device__ __forceinline__ void gemm_core32(const u16* __restrict__ A,
                                            const u16* __restrict__ Bw,
                                            const float* __restrict__ bias,
                                            void* __restrict__ outp, bool trans,
                                            int m0, int n0) {
  __shared__ u16 lA[128 * 64];
  __shared__ u16 lB[NT * 64 * 64];
  const int tid = threadIdx.x;
  const int lane = tid & 63, w = tid >> 6;
  const int wm = w >> 1, wn = w & 1;
  const int l32 = lane & 31, hi = lane >> 5;
  const int rg = lane >> 3, cs = lane & 7;

  f32x16 acc[2][NT];
#pragma unroll
  for (int i = 0; i < 2; ++i)
#pragma unroll
    for (int j = 0; j < NT; ++j)
#pragma unroll
      for (int e = 0; e < 16; ++e) acc[i][j][e] = 0.f;

  for (int it = 0; it < 16; ++it) {
    const int k0 = it * 64;
#pragma unroll
    for (int t = 0; t < 4; ++t) {
      const int row = w * 32 + t * 8 + rg;
      const int c = cs ^ (row & 7);
      async_copy16(A + (size_t)(m0 + row) * 1024 + k0 + c * 8, &lA[(w * 32 + t * 8) * 64]);
    }
#pragma unroll
    for (int t = 0; t < NT * 2; ++t) {
      const int row = w * (NT * 16) + t * 8 + rg;
      const int c = cs ^ (row & 7);
      async_copy16(Bw + (size_t)(n0 + row) * 1024 + k0 + c * 8,
                   &lB[(w * (NT * 16) + t * 8) * 64]);
    }
    __syncthreads();
#pragma unroll
    for (int s = 0; s < 4; ++s) {
      bf16x8 af[2], bfr[NT];
#pragma unroll
      for (int i = 0; i < 2; ++i) {
        const int row = wm * 64 + i * 32 + l32;
        af[i] = *(const bf16x8*)&lA[row * 64 + (((s * 2 + hi) ^ (row & 7)) * 8)];
      }
#pragma unroll
      for (int j = 0; j < NT; ++j) {
        const int row = wn * (NT * 32) + j * 32 + l32;
        bfr[j] = *(const bf16x8*)&lB[row * 64 + (((s * 2 + hi) ^ (row & 7)) * 8)];
      }
#pragma unroll
      for (int i = 0; i < 2; ++i)
#pragma unroll
        for (int j = 0; j < NT; ++j)
          acc[i][j] = __builtin_amdgcn_mfma_f32_32x32x16_bf16(af[i], bfr[j], acc[i][j], 0, 0, 0);
    }
    __syncthreads();
  }

#pragma unroll
  for (int j = 0; j < NT; ++j) {
    const int cg = n0 + wn * (NT * 32) + j * 32 + l32;
    const float bj = bias[cg];
#pragma unroll
    for (int i = 0; i < 2; ++i) {
      const int mbase = m0 + wm * 64 + i * 32 + 4 * hi;
#pragma unroll
      for (int g = 0; g < 4; ++g) {
        const int r0 = mbase + 8 * g;
        if (!trans) {
          if (OUT_BF16) {
            u16* o = (u16*)outp;
#pragma unroll
            for (int rr = 0; rr < 4; ++rr)
              o[(size_t)(r0 + rr) * 1024 + cg] = f2bf(acc[i][j][g * 4 + rr] + bj);
          } else {
            float* o = (float*)outp;
#pragma unroll
            for (int rr = 0; rr < 4; ++rr)
              o[(size_t)(r0 + rr) * 1024 + cg] = acc[i][j][g * 4 + rr] + bj;
          }
        } else {
          u16* o = (u16*)outp;
          const int bh = ((r0 >> 10) << 4) + (cg >> 6);
          const int g2 = (r0 & 1023) >> 2;
          const int d  = cg & 63;
          union { us4_t s; unsigned int u[2]; } pk;
          pk.u[0] = pack2bf(acc[i][j][g * 4 + 0] + bj, acc[i][j][g * 4 + 1] + bj);
          pk.u[1] = pack2bf(acc[i][j][g * 4 + 2] + bj, acc[i][j][g * 4 + 3] + bj);
          *(us4_t*)&o[(size_t)bh * 65536 + g2 * 256 + d * 4] = pk.s;
        }
      }
    }
  }
}

// out: grid 256 flat; 32 m-tiles x 8 n-tiles of 128x128 (NT=2). Each XCD owns
// 4 m-bands x 8 n (bijective: 256 % 8 == 0).
__global__ __launch_bounds__(256, 3) void out_gemm(
    const u16* __restrict__ A, const u16* __restrict__ W,
    const float* __restrict__ bias, float* __restrict__ out) {
  const int flat = blockIdx.x;
  const int xcd = flat & 7, t = flat >> 3;       // t 0..31
  const int n = t & 7, m = xcd * 4 + (t >> 3);   // m 0..31, n 0..7
  gemm_core32<false, 2>(A, W, bias, out, false, m * 128, n * 128);
}

// ---------------- flash attention, S^T orientation, no running max ------------
// R6: R4's global_load_lds staging verbatim + T5 setprio around MFMA clusters.
__global__ __launch_bounds__(256, 4) void attn_kernel(
    const u16* __restrict__ Qb, const u16* __restrict__ Kb, const u16* __restrict__ Vtb,
    const float* __restrict__ biasf, u16* __restrict__ Ob) {
  __shared__ u16 lK[128 * 64];
  __shared__ u16 lV[64 * 128];  // Vt2 slab, identity layout
  u16* lQ = lV;                 // prologue-only alias

  const int tid = threadIdx.x;
  const int lane = tid & 63, w = tid >> 6;
  const int quad = lane >> 4, l16 = lane & 15;
  const int rg = lane >> 3, cs = lane & 7;

  const int flat = blockIdx.x;
  const int xcd = flat & 7, r = flat >> 3;
  const int bh = xcd * 8 + (r & 7), qt = r >> 3;
  const int b = bh >> 4;
  const size_t qkBase = (size_t)b * 1048576 + (size_t)(bh & 15) * 64;
  const size_t vBase = (size_t)bh * 65536;
  const float C = 0.0450842200277982f;  // (1/sqrt(E)) * log2(e)
  const float* bp = biasf + b * 1024 + quad * 4;

#pragma unroll
  for (int t = 0; t < 2; ++t) {
    const int row = w * 16 + t * 8 + rg;
    const int c = cs ^ (row & 7);
    async_copy16(Qb + qkBase + (size_t)(qt * 64 + row) * 1024 + c * 8,
                 &lQ[(w * 16 + t * 8) * 64]);
  }
  __syncthreads();

  bf16x8 qf[2];
#pragma unroll
  for (int kk = 0; kk < 2; ++kk) {
    const int row = w * 16 + l16;
    qf[kk] = *(const bf16x8*)&lQ[row * 64 + (((kk * 4 + quad) ^ (row & 7)) * 8)];
  }
  __syncthreads();  // protect lQ before lV staging overwrites it

  float lsum = 0.f;
  f32x4 oacc[4];
#pragma unroll
  for (int dt = 0; dt < 4; ++dt) oacc[dt] = zero4();

  for (int it = 0; it < 8; ++it) {
    const int k0 = it * 128;
#pragma unroll
    for (int t = 0; t < 4; ++t) {
      const int row = w * 32 + t * 8 + rg;
      const int c = cs ^ (row & 7);
      async_copy16(Kb + qkBase + (size_t)(k0 + row) * 1024 + c * 8,
                   &lK[(w * 32 + t * 8) * 64]);
    }
#pragma unroll
    for (int t = 0; t < 4; ++t) {
      const int o16 = (w * 4 + t) * 512 + lane * 8;
      async_copy16(Vtb + vBase + (size_t)it * 8192 + o16, &lV[(w * 4 + t) * 512]);
    }
    __syncthreads();

    f32x4 sacc[8];
#pragma unroll
    for (int n = 0; n < 8; ++n) sacc[n] = zero4();
    __builtin_amdgcn_s_setprio(1);
#pragma unroll
    for (int kk = 0; kk < 2; ++kk) {
#pragma unroll
      for (int n = 0; n < 8; ++n) {
        const int row = n * 16 + l16;
        bf16x8 kf = *(const bf16x8*)&lK[row * 64 + (((kk * 4 + quad) ^ (row & 7)) * 8)];
        sacc[n] = __builtin_amdgcn_mfma_f32_16x16x32_bf16(kf, qf[kk], sacc[n], 0, 0, 0);
      }
    }
    __builtin_amdgcn_s_setprio(0);

    f32x4 sum4 = zero4();
#pragma unroll
    for (int n = 0; n < 8; ++n) {
      const float4 vb = *(const float4*)&bp[k0 + n * 16];
      sacc[n][0] = __builtin_amdgcn_exp2f(fmaf(sacc[n][0], C, vb.x));
      sacc[n][1] = __builtin_amdgcn_exp2f(fmaf(sacc[n][1], C, vb.y));
      sacc[n][2] = __builtin_amdgcn_exp2f(fmaf(sacc[n][2], C, vb.z));
      sacc[n][3] = __builtin_amdgcn_exp2f(fmaf(sacc[n][3], C, vb.w));
      sum4[0] += sacc[n][0]; sum4[1] += sacc[n][1];
      sum4[2] += sacc[n][2]; sum4[3] += sacc[n][3];
    }
    float rs = (sum4[0] + sum4[1]) + (sum4[2] + sum4[3]);
    rs += __shfl_xor(rs, 16);
    rs += __shfl_xor(rs, 32);
    lsum += rs;

    s16x4 pf[8];
#pragma unroll
    for (int n = 0; n < 8; ++n) {
      union { s16x4 v; unsigned int u[2]; } pu;
      pu.u[0] = pack2bf(sacc[n][0], sacc[n][1]);
      pu.u[1] = pack2bf(sacc[n][2], sacc[n][3]);
      pf[n] = pu.v;
    }

    __builtin_amdgcn_s_setprio(1);
#pragma unroll
    for (int dt = 0; dt < 4; ++dt) {
      const int dbase = (dt * 16 + l16) * 4;
#pragma unroll
      for (int ks = 0; ks < 8; ++ks) {
        s16x4 vf = *(const s16x4*)&lV[(ks * 4 + quad) * 256 + dbase];
        oacc[dt] = __builtin_amdgcn_mfma_f32_16x16x16bf16_1k(vf, pf[ks], oacc[dt], 0, 0, 0);
      }
    }
    __builtin_amdgcn_s_setprio(0);
    __syncthreads();
  }

  const float inv = 1.f / lsum;
  const int qg = qt * 64 + w * 16 + l16;
#pragma unroll
  for (int dt = 0; dt < 4; ++dt) {
    union { us4_t s; unsigned int u[2]; } pk;
    pk.u[0] = pack2bf(oacc[dt][0] * inv, oacc[dt][1] * inv);
    pk.u[1] = pack2bf(oacc[dt][2] * inv, oacc[dt][3] * inv);
    *(us4_t*)&Ob[qkBase + (size_t)qg * 1024 + dt * 16 + quad * 4] = pk.s;
  }
}

extern "C" void kernel_launch(void* const* d_in, const int* in_sizes, int n_in,
                              void* d_out, int out_size, void* d_ws, size_t ws_size,
                              hipStream_t stream) {
  const float* value  = (const float*)d_in[0];
  const float* key_in = (const float*)d_in[1];
  const float* query  = (const float*)d_in[2];
  const int*   mask   = (const int*)d_in[3];
  const float* Wq = (const float*)d_in[4];
  const float* bq = (const float*)d_in[5];
  const float* Wk = (const float*)d_in[6];
  const float* bk = (const float*)d_in[7];
  const float* Wv = (const float*)d_in[8];
  const float* bv = (const float*)d_in[9];
  const float* Wo = (const float*)d_in[10];
  const float* bo = (const float*)d_in[11];

  u16* ws = (u16*)d_ws;
  u16* q_bf  = ws;              // 4096x1024
  u16* k_bf  = ws + 4194304;
  u16* v_bf  = ws + 8388608;
  u16* wq_bf = ws + 12582912;   // 1024x1024 each
  u16* wk_bf = ws + 13631488;
  u16* wv_bf = ws + 14680064;
  u16* wo_bf = ws + 15728640;
  u16* Qbuf  = ws + 16777216;   // (b,s,h*64+d)
  u16* Kbuf  = ws + 20971520;
  u16* Vtbuf = ws + 25165824;   // Vt2[bh][s>>2][d][s&3]
  u16* attnb = ws + 29360128;   // (b,s,h*64+d)
  float* biasf = (float*)d_out; // consumed by attn, then overwritten by out_gemm

  fused_cast<<<16400, 256, 0, stream>>>(query, key_in, value, Wq, Wk, Wv, Wo, mask,
                                        q_bf, k_bf, v_bf, wq_bf, wk_bf, wv_bf, wo_bf,
                                        biasf);
  qkv_gemm256<<<dim3(192), 512, 0, stream>>>(q_bf, k_bf, v_bf, wq_bf, wk_bf, wv_bf,
                                             bq, bk, bv, Qbuf, Kbuf, Vtbuf);
  attn_kernel<<<dim3(1024), 256, 0, stream>>>(Qbuf, Kbuf, Vtbuf, biasf, attnb);
  out_gemm<<<dim3(256), 256, 0, stream>>>(attnb, wo_bf, bo, (float*)d_out);
}

// Round 7
// 206.494 us; speedup vs baseline: 1.3146x; 1.0154x over previous
//
#include <hip/hip_runtime.h>

// MHA: B=4, S=1024, E=1024, H=16, D=64.
// cast f32->bf16 + mask bias -> fused QKV GEMM (128x128 tile, 768 blocks =
// 3/CU 100% fill, triple-buffered counted-vmcnt pipeline, 32x32x16 MFMA,
// conflict-free k-step swizzle, XCD swizzle) -> flash attention (S^T,
// global_load_lds staging + T5 setprio) -> output GEMM (128x64 single-buffer).
// R7: R4's 256^2 grid was 192 blocks = 1 block/CU -> 64 of 256 CUs idle
// (Occupancy 13%). 128^2 tiles give 768 blocks = exactly 3/CU. Pipeline kept:
// stage unit = one 32-k step (4 gll/wave), issued 2 steps ahead into a 3-deep
// LDS ring (48 KiB), GATE(4) per step (never drains until the last step).
// Swizzle pc = c ^ ((row>>1)&3) identical to R4 (row stride 64B). out_gemm
// reverted to the R4-proven NT=1/512-block config. attn = R6 (gll + setprio).

typedef unsigned short u16;
typedef __bf16 bf16x8 __attribute__((ext_vector_type(8)));
typedef __bf16 bf16x2 __attribute__((ext_vector_type(2)));
typedef short s16x4 __attribute__((ext_vector_type(4)));
typedef float f32x4 __attribute__((ext_vector_type(4)));
typedef float f32x16 __attribute__((ext_vector_type(16)));

struct alignas(8) us4_t { u16 x, y, z, w; };

__device__ __forceinline__ u16 f2bf(float x) {
  unsigned int u = __builtin_bit_cast(unsigned int, x);
  unsigned int r = u + 0x7fffu + ((u >> 16) & 1u);
  return (u16)(r >> 16);
}

__device__ __forceinline__ unsigned int pack2bf(float a, float b) {
#if __has_builtin(__builtin_amdgcn_cvt_pk_bf16_f32)
  bf16x2 r = __builtin_amdgcn_cvt_pk_bf16_f32(a, b);
  return __builtin_bit_cast(unsigned int, r);
#else
  return (unsigned int)f2bf(a) | ((unsigned int)f2bf(b) << 16);
#endif
}

__device__ __forceinline__ f32x4 zero4() {
  f32x4 z; z[0] = 0.f; z[1] = 0.f; z[2] = 0.f; z[3] = 0.f; return z;
}

__device__ __forceinline__ void async_copy16(const void* g, void* l) {
  __builtin_amdgcn_global_load_lds(
      (__attribute__((address_space(1))) void*)(uintptr_t)g,
      (__attribute__((address_space(3))) void*)l, 16, 0, 0);
}

// Gate: wait until only the newest N vmem ops are outstanding, then barrier.
#define GATE(N)                                                         \
  do {                                                                  \
    asm volatile("s_waitcnt vmcnt(" #N ")\n\ts_barrier" ::: "memory");  \
    __builtin_amdgcn_sched_barrier(0);                                  \
  } while (0)

// ---------------- fused cast: 7 tensors + mask->additive bias (log2 domain) ----
__global__ void fused_cast(const float* __restrict__ q, const float* __restrict__ k,
                           const float* __restrict__ v, const float* __restrict__ wq,
                           const float* __restrict__ wk, const float* __restrict__ wv,
                           const float* __restrict__ wo, const int* __restrict__ mask,
                           u16* __restrict__ qo, u16* __restrict__ ko, u16* __restrict__ vo,
                           u16* __restrict__ wqo, u16* __restrict__ wko, u16* __restrict__ wvo,
                           u16* __restrict__ woo, float* __restrict__ biasf) {
  const int blk = blockIdx.x;
  if (blk >= 16384) {
    int i = (blk - 16384) * 256 + threadIdx.x;  // 0..4095
    biasf[i] = mask[i] ? 0.f : -1.4427e20f;
    return;
  }
  const float* src; u16* dst; int off;
  if (blk < 4096)       { src = q;  dst = qo;  off = blk; }
  else if (blk < 8192)  { src = k;  dst = ko;  off = blk - 4096; }
  else if (blk < 12288) { src = v;  dst = vo;  off = blk - 8192; }
  else if (blk < 13312) { src = wq; dst = wqo; off = blk - 12288; }
  else if (blk < 14336) { src = wk; dst = wko; off = blk - 13312; }
  else if (blk < 15360) { src = wv; dst = wvo; off = blk - 14336; }
  else                  { src = wo; dst = woo; off = blk - 15360; }
  const size_t i = (size_t)off * 256 + threadIdx.x;
  float4 f = ((const float4*)src)[i];
  unsigned int lo = pack2bf(f.x, f.y), hi = pack2bf(f.z, f.w);
  unsigned long long pk = (unsigned long long)lo | ((unsigned long long)hi << 32);
  ((unsigned long long*)dst)[i] = pk;
}

// ---------------- qkv GEMM: 128x128 tile, 3-deep counted-vmcnt pipeline ------
// C[i,o] = sum_e A[i,e]*W[o,e] + bias[o].  BM=BN=128, step K=32, 256 thr =
// 4 waves (2m x 2n), wave tile 64x64 = 2x2 frags of 32x32, MFMA 32x32x16.
// A/B operand frag: row|col = lane&31, k = (lane>>5)*8 + j (chunk ks*2+hi).
// C/D frag: col = lane&31, row = (reg&3) + 8*(reg>>2) + 4*(lane>>5).
// LDS ring [3 buf][128 row][32 u16] per operand (8 KiB/slab, 48 KiB total).
// Swizzle: chunk c stored at pc = c ^ ((row>>1)&3); row stride 64B = 16 words
// -> bank = 16*(row&1) + 4*pc covers all 8 bank-quads per 16-lane group.
// Stage unit = one step of both operands = 4 gll/wave, linear dest,
// pre-swizzled global source. Loop: GATE(4) -> stage(s+2) -> ds_read frags
// of step s -> 8 MFMAs (setprio). 2-step prefetch depth; drain only at s=31.
__global__ __launch_bounds__(256, 3) void qkv_gemm128(
    const u16* __restrict__ Xq, const u16* __restrict__ Xk, const u16* __restrict__ Xv,
    const u16* __restrict__ Wq, const u16* __restrict__ Wk, const u16* __restrict__ Wv,
    const float* __restrict__ bq, const float* __restrict__ bk, const float* __restrict__ bv,
    u16* __restrict__ Qo, u16* __restrict__ Ko, u16* __restrict__ Vto) {
  __shared__ u16 lA[3][4096];
  __shared__ u16 lB[3][4096];

  const int tid = threadIdx.x;
  const int lane = tid & 63, w = tid >> 6;   // 4 waves
  const int wm = w >> 1, wn = w & 1;         // 2 x 2
  const int l32 = lane & 31, hi = lane >> 5;

  // XCD swizzle: 768 blocks, 96 per XCD (bijective). Within an XCD, n cycles
  // fastest -> 8 n-blocks of one m-band share the A-panel in that XCD's L2.
  const int flat = blockIdx.x;
  const int xcd = flat & 7, i = flat >> 3;   // i 0..95
  const int g = xcd * 96 + i;                // 0..767
  const int n = g & 7, mt = g >> 3;          // mt 0..95
  const int z = mt >> 5, m = mt & 31;
  const u16* A = (z == 0) ? Xq : (z == 1) ? Xk : Xv;
  const u16* W = (z == 0) ? Wq : (z == 1) ? Wk : Wv;
  const float* bias = (z == 0) ? bq : (z == 1) ? bk : bv;
  u16* out = (z == 0) ? Qo : (z == 1) ? Ko : Vto;
  const bool trans = (z == 2);
  const int m0 = m * 128, n0 = n * 128;

  f32x4 accv[2][2][4];
  f32x16 acc[2][2];
#pragma unroll
  for (int a2 = 0; a2 < 2; ++a2)
#pragma unroll
    for (int b2 = 0; b2 < 2; ++b2)
#pragma unroll
      for (int e = 0; e < 16; ++e) acc[a2][b2][e] = 0.f;
  (void)accv;

  // Stage-source offsets (u16 elems). Load t2 covers rows (t2*4+w)*16..+15;
  // lane l -> row = r0 + (l>>2), stored pc = l&3; stored chunk must be
  // c2 = pc ^ ((row>>1)&3) = (l&3) ^ ((l>>3)&3)  (r0 multiple of 16).
  int offA[2], offB[2];
#pragma unroll
  for (int t2 = 0; t2 < 2; ++t2) {
    const int row = (t2 * 4 + w) * 16 + (lane >> 2);
    const int c2 = (lane & 3) ^ ((lane >> 3) & 3);
    offA[t2] = (m0 + row) * 1024 + c2 * 8;
    offB[t2] = (n0 + row) * 1024 + c2 * 8;
  }

  auto stg = [&](int buf, int s) {
    const int k0 = s * 32;
#pragma unroll
    for (int t2 = 0; t2 < 2; ++t2)
      async_copy16(A + (offA[t2] + k0), &lA[buf][(t2 * 4 + w) * 512]);
#pragma unroll
    for (int t2 = 0; t2 < 2; ++t2)
      async_copy16(W + (offB[t2] + k0), &lB[buf][(t2 * 4 + w) * 512]);
  };
  auto rdA = [&](int buf, int mf, int ks) -> bf16x8 {
    const int row = wm * 64 + mf * 32 + l32;
    const int pc = (ks * 2 + hi) ^ ((row >> 1) & 3);
    return *(const bf16x8*)&lA[buf][row * 32 + pc * 8];
  };
  auto rdB = [&](int buf, int nf, int ks) -> bf16x8 {
    const int row = wn * 64 + nf * 32 + l32;
    const int pc = (ks * 2 + hi) ^ ((row >> 1) & 3);
    return *(const bf16x8*)&lB[buf][row * 32 + pc * 8];
  };

  // Prologue: 2 steps in flight.
  stg(0, 0);
  stg(1, 1);

  int cb = 0;  // buffer of current step (s % 3)
  for (int s = 0; s < 32; ++s) {
    if (s < 31) { GATE(4); } else { GATE(0); }
    // issue-early: step s+2 into the slab last read at step s-1 (safe: those
    // ds_reads retired before each wave's MFMAs, hence before this barrier)
    if (s < 30) {
      int sb = cb + 2; if (sb >= 3) sb -= 3;
      stg(sb, s + 2);
    }
    bf16x8 af[2][2], bfr[2][2];
#pragma unroll
    for (int mf = 0; mf < 2; ++mf)
#pragma unroll
      for (int ks = 0; ks < 2; ++ks)
        af[mf][ks] = rdA(cb, mf, ks);
#pragma unroll
    for (int nf = 0; nf < 2; ++nf)
#pragma unroll
      for (int ks = 0; ks < 2; ++ks)
        bfr[nf][ks] = rdB(cb, nf, ks);
    __builtin_amdgcn_s_setprio(1);
#pragma unroll
    for (int ks = 0; ks < 2; ++ks)
#pragma unroll
      for (int mf = 0; mf < 2; ++mf)
#pragma unroll
        for (int nf = 0; nf < 2; ++nf)
          acc[mf][nf] = __builtin_amdgcn_mfma_f32_32x32x16_bf16(
              af[mf][ks], bfr[nf][ks], acc[mf][nf], 0, 0, 0);
    __builtin_amdgcn_s_setprio(0);
    cb = (cb == 2) ? 0 : cb + 1;
  }

  // ---- epilogue (32x32 C/D frag: col = l32, row = (reg&3)+8*(reg>>2)+4*hi) --
#pragma unroll
  for (int nf = 0; nf < 2; ++nf) {
    const int cg = n0 + wn * 64 + nf * 32 + l32;
    const float bj = bias[cg];
#pragma unroll
    for (int mf = 0; mf < 2; ++mf) {
      const int mbase = m0 + wm * 64 + mf * 32 + 4 * hi;
#pragma unroll
      for (int g2 = 0; g2 < 4; ++g2) {
        const int r0 = mbase + 8 * g2;
        if (!trans) {
#pragma unroll
          for (int rr = 0; rr < 4; ++rr)
            out[(size_t)(r0 + rr) * 1024 + cg] = f2bf(acc[mf][nf][g2 * 4 + rr] + bj);
        } else {
          // V store in PV-fragment order: Vt2[bh][s>>2][d][s&3]; r0 % 4 == 0.
          const int bh = ((r0 >> 10) << 4) + (cg >> 6);
          const int gq = (r0 & 1023) >> 2;
          const int d = cg & 63;
          union { us4_t s; unsigned int u[2]; } pk;
          pk.u[0] = pack2bf(acc[mf][nf][g2 * 4 + 0] + bj, acc[mf][nf][g2 * 4 + 1] + bj);
          pk.u[1] = pack2bf(acc[mf][nf][g2 * 4 + 2] + bj, acc[mf][nf][g2 * 4 + 3] + bj);
          *(us4_t*)&out[(size_t)bh * 65536 + gq * 256 + d * 4] = pk.s;
        }
      }
    }
  }
}

// ---------------- 128-row GEMM core (single-buffer), used by out_gemm --------
// C/D frag: col = lane&31, row = (reg&3) + 8*(reg>>2) + 4*(lane>>5).
template <bool OUT_BF16, int NT>
__device__ __forceinline__ void gemm_core32(const u16* __restrict__ A,
                                            const u16* __restrict__ Bw,
                                            const float* __restrict__ bias,
                                            void* __restrict__ outp, bool trans,
                                            int m0, int n0) {
  __shared__ u16 lA[128 * 64];
  __shared__ u16 lB[NT * 64 * 64];
  const int tid = threadIdx.x;
  const int lane = tid & 63, w = tid >> 6;
  const int wm = w >> 1, wn = w & 1;
  const int l32 = lane & 31, hi = lane >> 5;
  const int rg = lane >> 3, cs = lane & 7;

  f32x16 acc[2][NT];
#pragma unroll
  for (int i = 0; i < 2; ++i)
#pragma unroll
    for (int j = 0; j < NT; ++j)
#pragma unroll
      for (int e = 0; e < 16; ++e) acc[i][j][e] = 0.f;

  for (int it = 0; it < 16; ++it) {
    const int k0 = it * 64;
#pragma unroll
    for (int t = 0; t < 4; ++t) {
      const int row = w * 32 + t * 8 + rg;
      const int c = cs ^ (row & 7);
      async_copy16(A + (size_t)(m0 + row) * 1024 + k0 + c * 8, &lA[(w * 32 + t * 8) * 64]);
    }
#pragma unroll
    for (int t = 0; t < NT * 2; ++t) {
      const int row = w * (NT * 16) + t * 8 + rg;
      const int c = cs ^ (row & 7);
      async_copy16(Bw + (size_t)(n0 + row) * 1024 + k0 + c * 8,
                   &lB[(w * (NT * 16) + t * 8) * 64]);
    }
    __syncthreads();
#pragma unroll
    for (int s = 0; s < 4; ++s) {
      bf16x8 af[2], bfr[NT];
#pragma unroll
      for (int i = 0; i < 2; ++i) {
        const int row = wm * 64 + i * 32 + l32;
        af[i] = *(const bf16x8*)&lA[row * 64 + (((s * 2 + hi) ^ (row & 7)) * 8)];
      }
#pragma unroll
      for (int j = 0; j < NT; ++j) {
        const int row = wn * (NT * 32) + j * 32 + l32;
        bfr[j] = *(const bf16x8*)&lB[row * 64 + (((s * 2 + hi) ^ (row & 7)) * 8)];
      }
#pragma unroll
      for (int i = 0; i < 2; ++i)
#pragma unroll
        for (int j = 0; j < NT; ++j)
          acc[i][j] = __builtin_amdgcn_mfma_f32_32x32x16_bf16(af[i], bfr[j], acc[i][j], 0, 0, 0);
    }
    __syncthreads();
  }

#pragma unroll
  for (int j = 0; j < NT; ++j) {
    const int cg = n0 + wn * (NT * 32) + j * 32 + l32;
    const float bj = bias[cg];
#pragma unroll
    for (int i = 0; i < 2; ++i) {
      const int mbase = m0 + wm * 64 + i * 32 + 4 * hi;
#pragma unroll
      for (int g = 0; g < 4; ++g) {
        const int r0 = mbase + 8 * g;
        if (!trans) {
          if (OUT_BF16) {
            u16* o = (u16*)outp;
#pragma unroll
            for (int rr = 0; rr < 4; ++rr)
              o[(size_t)(r0 + rr) * 1024 + cg] = f2bf(acc[i][j][g * 4 + rr] + bj);
          } else {
            float* o = (float*)outp;
#pragma unroll
            for (int rr = 0; rr < 4; ++rr)
              o[(size_t)(r0 + rr) * 1024 + cg] = acc[i][j][g * 4 + rr] + bj;
          }
        } else {
          u16* o = (u16*)outp;
          const int bh = ((r0 >> 10) << 4) + (cg >> 6);
          const int g2 = (r0 & 1023) >> 2;
          const int d  = cg & 63;
          union { us4_t s; unsigned int u[2]; } pk;
          pk.u[0] = pack2bf(acc[i][j][g * 4 + 0] + bj, acc[i][j][g * 4 + 1] + bj);
          pk.u[1] = pack2bf(acc[i][j][g * 4 + 2] + bj, acc[i][j][g * 4 + 3] + bj);
          *(us4_t*)&o[(size_t)bh * 65536 + g2 * 256 + d * 4] = pk.s;
        }
      }
    }
  }
}

// out: grid 512 flat; xcd owns 4 m-bands of 16 n-blocks each (R4 config).
__global__ __launch_bounds__(256, 3) void out_gemm(
    const u16* __restrict__ A, const u16* __restrict__ W,
    const float* __restrict__ bias, float* __restrict__ out) {
  const int flat = blockIdx.x;
  const int xcd = flat & 7, t = flat >> 3;
  const int n = t & 15, m = xcd * 4 + (t >> 4);
  gemm_core32<false, 1>(A, W, bias, out, false, m * 128, n * 64);
}

// ---------------- flash attention, S^T orientation, no running max ------------
// R6 version: global_load_lds staging + T5 setprio around MFMA clusters.
__global__ __launch_bounds__(256, 4) void attn_kernel(
    const u16* __restrict__ Qb, const u16* __restrict__ Kb, const u16* __restrict__ Vtb,
    const float* __restrict__ biasf, u16* __restrict__ Ob) {
  __shared__ u16 lK[128 * 64];
  __shared__ u16 lV[64 * 128];  // Vt2 slab, identity layout
  u16* lQ = lV;                 // prologue-only alias

  const int tid = threadIdx.x;
  const int lane = tid & 63, w = tid >> 6;
  const int quad = lane >> 4, l16 = lane & 15;
  const int rg = lane >> 3, cs = lane & 7;

  const int flat = blockIdx.x;
  const int xcd = flat & 7, r = flat >> 3;
  const int bh = xcd * 8 + (r & 7), qt = r >> 3;
  const int b = bh >> 4;
  const size_t qkBase = (size_t)b * 1048576 + (size_t)(bh & 15) * 64;
  const size_t vBase = (size_t)bh * 65536;
  const float C = 0.0450842200277982f;  // (1/sqrt(E)) * log2(e)
  const float* bp = biasf + b * 1024 + quad * 4;

#pragma unroll
  for (int t = 0; t < 2; ++t) {
    const int row = w * 16 + t * 8 + rg;
    const int c = cs ^ (row & 7);
    async_copy16(Qb + qkBase + (size_t)(qt * 64 + row) * 1024 + c * 8,
                 &lQ[(w * 16 + t * 8) * 64]);
  }
  __syncthreads();

  bf16x8 qf[2];
#pragma unroll
  for (int kk = 0; kk < 2; ++kk) {
    const int row = w * 16 + l16;
    qf[kk] = *(const bf16x8*)&lQ[row * 64 + (((kk * 4 + quad) ^ (row & 7)) * 8)];
  }
  __syncthreads();  // protect lQ before lV staging overwrites it

  float lsum = 0.f;
  f32x4 oacc[4];
#pragma unroll
  for (int dt = 0; dt < 4; ++dt) oacc[dt] = zero4();

  for (int it = 0; it < 8; ++it) {
    const int k0 = it * 128;
#pragma unroll
    for (int t = 0; t < 4; ++t) {
      const int row = w * 32 + t * 8 + rg;
      const int c = cs ^ (row & 7);
      async_copy16(Kb + qkBase + (size_t)(k0 + row) * 1024 + c * 8,
                   &lK[(w * 32 + t * 8) * 64]);
    }
#pragma unroll
    for (int t = 0; t < 4; ++t) {
      const int o16 = (w * 4 + t) * 512 + lane * 8;
      async_copy16(Vtb + vBase + (size_t)it * 8192 + o16, &lV[(w * 4 + t) * 512]);
    }
    __syncthreads();

    f32x4 sacc[8];
#pragma unroll
    for (int n = 0; n < 8; ++n) sacc[n] = zero4();
    __builtin_amdgcn_s_setprio(1);
#pragma unroll
    for (int kk = 0; kk < 2; ++kk) {
#pragma unroll
      for (int n = 0; n < 8; ++n) {
        const int row = n * 16 + l16;
        bf16x8 kf = *(const bf16x8*)&lK[row * 64 + (((kk * 4 + quad) ^ (row & 7)) * 8)];
        sacc[n] = __builtin_amdgcn_mfma_f32_16x16x32_bf16(kf, qf[kk], sacc[n], 0, 0, 0);
      }
    }
    __builtin_amdgcn_s_setprio(0);

    f32x4 sum4 = zero4();
#pragma unroll
    for (int n = 0; n < 8; ++n) {
      const float4 vb = *(const float4*)&bp[k0 + n * 16];
      sacc[n][0] = __builtin_amdgcn_exp2f(fmaf(sacc[n][0], C, vb.x));
      sacc[n][1] = __builtin_amdgcn_exp2f(fmaf(sacc[n][1], C, vb.y));
      sacc[n][2] = __builtin_amdgcn_exp2f(fmaf(sacc[n][2], C, vb.z));
      sacc[n][3] = __builtin_amdgcn_exp2f(fmaf(sacc[n][3], C, vb.w));
      sum4[0] += sacc[n][0]; sum4[1] += sacc[n][1];
      sum4[2] += sacc[n][2]; sum4[3] += sacc[n][3];
    }
    float rs = (sum4[0] + sum4[1]) + (sum4[2] + sum4[3]);
    rs += __shfl_xor(rs, 16);
    rs += __shfl_xor(rs, 32);
    lsum += rs;

    s16x4 pf[8];
#pragma unroll
    for (int n = 0; n < 8; ++n) {
      union { s16x4 v; unsigned int u[2]; } pu;
      pu.u[0] = pack2bf(sacc[n][0], sacc[n][1]);
      pu.u[1] = pack2bf(sacc[n][2], sacc[n][3]);
      pf[n] = pu.v;
    }

    __builtin_amdgcn_s_setprio(1);
#pragma unroll
    for (int dt = 0; dt < 4; ++dt) {
      const int dbase = (dt * 16 + l16) * 4;
#pragma unroll
      for (int ks = 0; ks < 8; ++ks) {
        s16x4 vf = *(const s16x4*)&lV[(ks * 4 + quad) * 256 + dbase];
        oacc[dt] = __builtin_amdgcn_mfma_f32_16x16x16bf16_1k(vf, pf[ks], oacc[dt], 0, 0, 0);
      }
    }
    __builtin_amdgcn_s_setprio(0);
    __syncthreads();
  }

  const float inv = 1.f / lsum;
  const int qg = qt * 64 + w * 16 + l16;
#pragma unroll
  for (int dt = 0; dt < 4; ++dt) {
    union { us4_t s; unsigned int u[2]; } pk;
    pk.u[0] = pack2bf(oacc[dt][0] * inv, oacc[dt][1] * inv);
    pk.u[1] = pack2bf(oacc[dt][2] * inv, oacc[dt][3] * inv);
    *(us4_t*)&Ob[qkBase + (size_t)qg * 1024 + dt * 16 + quad * 4] = pk.s;
  }
}

extern "C" void kernel_launch(void* const* d_in, const int* in_sizes, int n_in,
                              void* d_out, int out_size, void* d_ws, size_t ws_size,
                              hipStream_t stream) {
  const float* value  = (const float*)d_in[0];
  const float* key_in = (const float*)d_in[1];
  const float* query  = (const float*)d_in[2];
  const int*   mask   = (const int*)d_in[3];
  const float* Wq = (const float*)d_in[4];
  const float* bq = (const float*)d_in[5];
  const float* Wk = (const float*)d_in[6];
  const float* bk = (const float*)d_in[7];
  const float* Wv = (const float*)d_in[8];
  const float* bv = (const float*)d_in[9];
  const float* Wo = (const float*)d_in[10];
  const float* bo = (const float*)d_in[11];

  u16* ws = (u16*)d_ws;
  u16* q_bf  = ws;              // 4096x1024
  u16* k_bf  = ws + 4194304;
  u16* v_bf  = ws + 8388608;
  u16* wq_bf = ws + 12582912;   // 1024x1024 each
  u16* wk_bf = ws + 13631488;
  u16* wv_bf = ws + 14680064;
  u16* wo_bf = ws + 15728640;
  u16* Qbuf  = ws + 16777216;   // (b,s,h*64+d)
  u16* Kbuf  = ws + 20971520;
  u16* Vtbuf = ws + 25165824;   // Vt2[bh][s>>2][d][s&3]
  u16* attnb = ws + 29360128;   // (b,s,h*64+d)
  float* biasf = (float*)d_out; // consumed by attn, then overwritten by out_gemm

  fused_cast<<<16400, 256, 0, stream>>>(query, key_in, value, Wq, Wk, Wv, Wo, mask,
                                        q_bf, k_bf, v_bf, wq_bf, wk_bf, wv_bf, wo_bf,
                                        biasf);
  qkv_gemm128<<<dim3(768), 256, 0, stream>>>(q_bf, k_bf, v_bf, wq_bf, wk_bf, wv_bf,
                                             bq, bk, bv, Qbuf, Kbuf, Vtbuf);
  attn_kernel<<<dim3(1024), 256, 0, stream>>>(Qbuf, Kbuf, Vtbuf, biasf, attnb);
  out_gemm<<<dim3(512), 256, 0, stream>>>(attnb, wo_bf, bo, (float*)d_out);
}

// Round 8
// 205.651 us; speedup vs baseline: 1.3200x; 1.0041x over previous
//
#include <hip/hip_runtime.h>

// MHA: B=4, S=1024, E=1024, H=16, D=64.
// R8: best-known assembly round.
//   qkv  = R4's 256x256 counted-vmcnt 4-phase pipeline (best measured 41.0-41.6us)
//   attn = R6's gll-staged flash attention + T5 setprio (<41.2us)
//   out  = R0's exact config: gemm_core32<NT=1>, 512 blocks, launch_bounds(256,2)
//   cast = unchanged.
// Purpose: field the best per-kernel configs together and test whether kernel
// deltas flow 1:1 into total (R0=200.3 had qkv=44.8; this has qkv=41.6).
// If total stays >=205 with counters at predicted values, the ~70us residual
// (cast + out + inter-kernel cost) is confirmed dominant -> attack it next.

typedef unsigned short u16;
typedef __bf16 bf16x8 __attribute__((ext_vector_type(8)));
typedef __bf16 bf16x2 __attribute__((ext_vector_type(2)));
typedef short s16x4 __attribute__((ext_vector_type(4)));
typedef float f32x4 __attribute__((ext_vector_type(4)));
typedef float f32x16 __attribute__((ext_vector_type(16)));

struct alignas(8) us4_t { u16 x, y, z, w; };

__device__ __forceinline__ u16 f2bf(float x) {
  unsigned int u = __builtin_bit_cast(unsigned int, x);
  unsigned int r = u + 0x7fffu + ((u >> 16) & 1u);
  return (u16)(r >> 16);
}

__device__ __forceinline__ unsigned int pack2bf(float a, float b) {
#if __has_builtin(__builtin_amdgcn_cvt_pk_bf16_f32)
  bf16x2 r = __builtin_amdgcn_cvt_pk_bf16_f32(a, b);
  return __builtin_bit_cast(unsigned int, r);
#else
  return (unsigned int)f2bf(a) | ((unsigned int)f2bf(b) << 16);
#endif
}

__device__ __forceinline__ f32x4 zero4() {
  f32x4 z; z[0] = 0.f; z[1] = 0.f; z[2] = 0.f; z[3] = 0.f; return z;
}

__device__ __forceinline__ void async_copy16(const void* g, void* l) {
  __builtin_amdgcn_global_load_lds(
      (__attribute__((address_space(1))) void*)(uintptr_t)g,
      (__attribute__((address_space(3))) void*)l, 16, 0, 0);
}

// Gate: wait until only the newest N vmem ops are outstanding, then barrier.
#define GATE(N)                                                         \
  do {                                                                  \
    asm volatile("s_waitcnt vmcnt(" #N ")\n\ts_barrier" ::: "memory");  \
    __builtin_amdgcn_sched_barrier(0);                                  \
  } while (0)

// ---------------- fused cast: 7 tensors + mask->additive bias (log2 domain) ----
__global__ void fused_cast(const float* __restrict__ q, const float* __restrict__ k,
                           const float* __restrict__ v, const float* __restrict__ wq,
                           const float* __restrict__ wk, const float* __restrict__ wv,
                           const float* __restrict__ wo, const int* __restrict__ mask,
                           u16* __restrict__ qo, u16* __restrict__ ko, u16* __restrict__ vo,
                           u16* __restrict__ wqo, u16* __restrict__ wko, u16* __restrict__ wvo,
                           u16* __restrict__ woo, float* __restrict__ biasf) {
  const int blk = blockIdx.x;
  if (blk >= 16384) {
    int i = (blk - 16384) * 256 + threadIdx.x;  // 0..4095
    biasf[i] = mask[i] ? 0.f : -1.4427e20f;
    return;
  }
  const float* src; u16* dst; int off;
  if (blk < 4096)       { src = q;  dst = qo;  off = blk; }
  else if (blk < 8192)  { src = k;  dst = ko;  off = blk - 4096; }
  else if (blk < 12288) { src = v;  dst = vo;  off = blk - 8192; }
  else if (blk < 13312) { src = wq; dst = wqo; off = blk - 12288; }
  else if (blk < 14336) { src = wk; dst = wko; off = blk - 13312; }
  else if (blk < 15360) { src = wv; dst = wvo; off = blk - 14336; }
  else                  { src = wo; dst = woo; off = blk - 15360; }
  const size_t i = (size_t)off * 256 + threadIdx.x;
  float4 f = ((const float4*)src)[i];
  unsigned int lo = pack2bf(f.x, f.y), hi = pack2bf(f.z, f.w);
  unsigned long long pk = (unsigned long long)lo | ((unsigned long long)hi << 32);
  ((unsigned long long*)dst)[i] = pk;
}

// 8 independent 32x32x16 MFMAs (2mf x 2nf x 2ks) with setprio wrap (T5).
template <int MLO>
__device__ __forceinline__ void mm8(f32x16 (&acc)[4][2], const bf16x8 (&af)[2][2],
                                    const bf16x8 (&bfr)[2][2]) {
  __builtin_amdgcn_s_setprio(1);
#pragma unroll
  for (int ks = 0; ks < 2; ++ks)
#pragma unroll
    for (int mf = 0; mf < 2; ++mf)
#pragma unroll
      for (int nf = 0; nf < 2; ++nf)
        acc[MLO + mf][nf] = __builtin_amdgcn_mfma_f32_32x32x16_bf16(
            af[mf][ks], bfr[nf][ks], acc[MLO + mf][nf], 0, 0, 0);
  __builtin_amdgcn_s_setprio(0);
}

// ---------------- qkv GEMM: 256x256 tile, counted-vmcnt 4-phase pipeline -----
// (R4 verbatim; best measured. Residual 2.36M bank conflicts = 4 cy/read.)
__global__ __launch_bounds__(512, 2) void qkv_gemm256(
    const u16* __restrict__ Xq, const u16* __restrict__ Xk, const u16* __restrict__ Xv,
    const u16* __restrict__ Wq, const u16* __restrict__ Wk, const u16* __restrict__ Wv,
    const float* __restrict__ bq, const float* __restrict__ bk, const float* __restrict__ bv,
    u16* __restrict__ Qo, u16* __restrict__ Ko, u16* __restrict__ Vto) {
  __shared__ u16 lA[2][2][256 * 32];
  __shared__ u16 lB[2][2][256 * 32];

  const int tid = threadIdx.x;
  const int lane = tid & 63, w = tid >> 6;   // 8 waves
  const int wm = w >> 2, wn = w & 3;         // 2 x 4
  const int l32 = lane & 31, hi = lane >> 5;

  // XCD swizzle: 192 blocks, 24 per XCD (bijective).
  const int flat = blockIdx.x;
  const int xcd = flat & 7, t = flat >> 3;   // t 0..23
  const int g = xcd * 24 + t;                // 0..191
  const int mt = g >> 2, n = g & 3;          // mt 0..47
  const int z = mt >> 4, m = mt & 15;
  const u16* A = (z == 0) ? Xq : (z == 1) ? Xk : Xv;
  const u16* W = (z == 0) ? Wq : (z == 1) ? Wk : Wv;
  const float* bias = (z == 0) ? bq : (z == 1) ? bk : bv;
  u16* out = (z == 0) ? Qo : (z == 1) ? Ko : Vto;
  const bool trans = (z == 2);
  const int m0 = m * 256, n0 = n * 256;

  f32x16 acc[4][2];
#pragma unroll
  for (int i = 0; i < 4; ++i)
#pragma unroll
    for (int j = 0; j < 2; ++j)
#pragma unroll
      for (int e = 0; e < 16; ++e) acc[i][j][e] = 0.f;

  int offA[2], offB[2];
#pragma unroll
  for (int t2 = 0; t2 < 2; ++t2) {
    const int row = (t2 * 8 + w) * 16 + (lane >> 2);
    const int c2 = (lane & 3) ^ ((lane >> 3) & 3);
    offA[t2] = (m0 + row) * 1024 + c2 * 8;
    offB[t2] = (n0 + row) * 1024 + c2 * 8;
  }

  const u16* cA = &lA[0][0][0];
  const u16* cB = &lB[0][0][0];
  u16* nA = (u16*)&lA[1][0][0];
  u16* nB = (u16*)&lB[1][0][0];

  auto stA = [&](u16* dst, int h, int k0) {
#pragma unroll
    for (int t2 = 0; t2 < 2; ++t2)
      async_copy16(A + (offA[t2] + k0 + h * 32), dst + h * 8192 + (t2 * 8 + w) * 512);
  };
  auto stB = [&](u16* dst, int h, int k0) {
#pragma unroll
    for (int t2 = 0; t2 < 2; ++t2)
      async_copy16(W + (offB[t2] + k0 + h * 32), dst + h * 8192 + (t2 * 8 + w) * 512);
  };
  auto rd = [&](const u16* base, int h, int row, int ks) -> bf16x8 {
    const int pc = (ks * 2 + hi) ^ ((row >> 1) & 3);
    return *(const bf16x8*)&base[h * 8192 + row * 32 + pc * 8];
  };

  // Prologue: stage tile 0 in steady-state issue order {Ak0, Bk0, Ak1, Bk1}.
  stA((u16*)cA, 0, 0);
  stB((u16*)cB, 0, 0);
  stA((u16*)cA, 1, 0);
  stB((u16*)cB, 1, 0);

  bf16x8 af[2][2], bfr[2][2];
  for (int kt = 0; kt < 16; ++kt) {
    const bool st = (kt < 15);
    const int k1 = (kt + 1) * 64;

    // ---- phase 1: k-half 0, mf 0-1 ----
    GATE(4);  // {Ak0,Bk0}(kt) complete; {Ak1,Bk1}(kt) may be in flight
#pragma unroll
    for (int mf = 0; mf < 2; ++mf)
#pragma unroll
      for (int ks = 0; ks < 2; ++ks)
        af[mf][ks] = rd(cA, 0, wm * 128 + mf * 32 + l32, ks);
#pragma unroll
    for (int nf = 0; nf < 2; ++nf)
#pragma unroll
      for (int ks = 0; ks < 2; ++ks)
        bfr[nf][ks] = rd(cB, 0, wn * 64 + nf * 32 + l32, ks);
    if (st) stA(nA, 0, k1);
    mm8<0>(acc, af, bfr);

    // ---- phase 2: k-half 0, mf 2-3 (B frags reused in regs) ----
#pragma unroll
    for (int mf = 0; mf < 2; ++mf)
#pragma unroll
      for (int ks = 0; ks < 2; ++ks)
        af[mf][ks] = rd(cA, 0, wm * 128 + (2 + mf) * 32 + l32, ks);
    if (st) stB(nB, 0, k1);
    mm8<2>(acc, af, bfr);

    // ---- phase 3: k-half 1, mf 0-1 ----
    if (st) { GATE(4); } else { GATE(0); }  // {Ak1,Bk1}(kt) complete
#pragma unroll
    for (int mf = 0; mf < 2; ++mf)
#pragma unroll
      for (int ks = 0; ks < 2; ++ks)
        af[mf][ks] = rd(cA, 1, wm * 128 + mf * 32 + l32, ks);
#pragma unroll
    for (int nf = 0; nf < 2; ++nf)
#pragma unroll
      for (int ks = 0; ks < 2; ++ks)
        bfr[nf][ks] = rd(cB, 1, wn * 64 + nf * 32 + l32, ks);
    if (st) stA(nA, 1, k1);
    mm8<0>(acc, af, bfr);

    // ---- phase 4: k-half 1, mf 2-3 ----
#pragma unroll
    for (int mf = 0; mf < 2; ++mf)
#pragma unroll
      for (int ks = 0; ks < 2; ++ks)
        af[mf][ks] = rd(cA, 1, wm * 128 + (2 + mf) * 32 + l32, ks);
    if (st) stB(nB, 1, k1);
    mm8<2>(acc, af, bfr);

    // swap buffers
    const u16* tA = cA; cA = nA; nA = (u16*)tA;
    const u16* tB = cB; cB = nB; nB = (u16*)tB;
  }

  // ---- epilogue (32x32 C/D frag: col = l32, row = (reg&3)+8*(reg>>2)+4*hi) --
#pragma unroll
  for (int nf = 0; nf < 2; ++nf) {
    const int cg = n0 + wn * 64 + nf * 32 + l32;
    const float bj = bias[cg];
#pragma unroll
    for (int mf = 0; mf < 4; ++mf) {
      const int mbase = m0 + wm * 128 + mf * 32 + 4 * hi;
#pragma unroll
      for (int g2 = 0; g2 < 4; ++g2) {
        const int r0 = mbase + 8 * g2;
        if (!trans) {
#pragma unroll
          for (int rr = 0; rr < 4; ++rr)
            out[(size_t)(r0 + rr) * 1024 + cg] = f2bf(acc[mf][nf][g2 * 4 + rr] + bj);
        } else {
          // V store in PV-fragment order: Vt2[bh][s>>2][d][s&3]; r0 % 4 == 0.
          const int bh = ((r0 >> 10) << 4) + (cg >> 6);
          const int gq = (r0 & 1023) >> 2;
          const int d = cg & 63;
          union { us4_t s; unsigned int u[2]; } pk;
          pk.u[0] = pack2bf(acc[mf][nf][g2 * 4 + 0] + bj, acc[mf][nf][g2 * 4 + 1] + bj);
          pk.u[1] = pack2bf(acc[mf][nf][g2 * 4 + 2] + bj, acc[mf][nf][g2 * 4 + 3] + bj);
          *(us4_t*)&out[(size_t)bh * 65536 + gq * 256 + d * 4] = pk.s;
        }
      }
    }
  }
}

// ---------------- 128-row GEMM core (single-buffer), used by out_gemm --------
// C/D frag: col = lane&31, row = (reg&3) + 8*(reg>>2) + 4*(lane>>5).
template <bool OUT_BF16, int NT>
__device__ __forceinline__ void gemm_core32(const u16* __restrict__ A,
                                            const u16* __restrict__ Bw,
                                            const float* __restrict__ bias,
                                            void* __restrict__ outp, bool trans,
                                            int m0, int n0) {
  __shared__ u16 lA[128 * 64];
  __shared__ u16 lB[NT * 64 * 64];
  const int tid = threadIdx.x;
  const int lane = tid & 63, w = tid >> 6;
  const int wm = w >> 1, wn = w & 1;
  const int l32 = lane & 31, hi = lane >> 5;
  const int rg = lane >> 3, cs = lane & 7;

  f32x16 acc[2][NT];
#pragma unroll
  for (int i = 0; i < 2; ++i)
#pragma unroll
    for (int j = 0; j < NT; ++j)
#pragma unroll
      for (int e = 0; e < 16; ++e) acc[i][j][e] = 0.f;

  for (int it = 0; it < 16; ++it) {
    const int k0 = it * 64;
#pragma unroll
    for (int t = 0; t < 4; ++t) {
      const int row = w * 32 + t * 8 + rg;
      const int c = cs ^ (row & 7);
      async_copy16(A + (size_t)(m0 + row) * 1024 + k0 + c * 8, &lA[(w * 32 + t * 8) * 64]);
    }
#pragma unroll
    for (int t = 0; t < NT * 2; ++t) {
      const int row = w * (NT * 16) + t * 8 + rg;
      const int c = cs ^ (row & 7);
      async_copy16(Bw + (size_t)(n0 + row) * 1024 + k0 + c * 8,
                   &lB[(w * (NT * 16) + t * 8) * 64]);
    }
    __syncthreads();
#pragma unroll
    for (int s = 0; s < 4; ++s) {
      bf16x8 af[2], bfr[NT];
#pragma unroll
      for (int i = 0; i < 2; ++i) {
        const int row = wm * 64 + i * 32 + l32;
        af[i] = *(const bf16x8*)&lA[row * 64 + (((s * 2 + hi) ^ (row & 7)) * 8)];
      }
#pragma unroll
      for (int j = 0; j < NT; ++j) {
        const int row = wn * (NT * 32) + j * 32 + l32;
        bfr[j] = *(const bf16x8*)&lB[row * 64 + (((s * 2 + hi) ^ (row & 7)) * 8)];
      }
#pragma unroll
      for (int i = 0; i < 2; ++i)
#pragma unroll
        for (int j = 0; j < NT; ++j)
          acc[i][j] = __builtin_amdgcn_mfma_f32_32x32x16_bf16(af[i], bfr[j], acc[i][j], 0, 0, 0);
    }
    __syncthreads();
  }

#pragma unroll
  for (int j = 0; j < NT; ++j) {
    const int cg = n0 + wn * (NT * 32) + j * 32 + l32;
    const float bj = bias[cg];
#pragma unroll
    for (int i = 0; i < 2; ++i) {
      const int mbase = m0 + wm * 64 + i * 32 + 4 * hi;
#pragma unroll
      for (int g = 0; g < 4; ++g) {
        const int r0 = mbase + 8 * g;
        if (!trans) {
          if (OUT_BF16) {
            u16* o = (u16*)outp;
#pragma unroll
            for (int rr = 0; rr < 4; ++rr)
              o[(size_t)(r0 + rr) * 1024 + cg] = f2bf(acc[i][j][g * 4 + rr] + bj);
          } else {
            float* o = (float*)outp;
#pragma unroll
            for (int rr = 0; rr < 4; ++rr)
              o[(size_t)(r0 + rr) * 1024 + cg] = acc[i][j][g * 4 + rr] + bj;
          }
        } else {
          u16* o = (u16*)outp;
          const int bh = ((r0 >> 10) << 4) + (cg >> 6);
          const int g2 = (r0 & 1023) >> 2;
          const int d  = cg & 63;
          union { us4_t s; unsigned int u[2]; } pk;
          pk.u[0] = pack2bf(acc[i][j][g * 4 + 0] + bj, acc[i][j][g * 4 + 1] + bj);
          pk.u[1] = pack2bf(acc[i][j][g * 4 + 2] + bj, acc[i][j][g * 4 + 3] + bj);
          *(us4_t*)&o[(size_t)bh * 65536 + g2 * 256 + d * 4] = pk.s;
        }
      }
    }
  }
}

// out: grid 512 flat; xcd owns 4 m-bands of 16 n-blocks each (R0 exact config).
__global__ __launch_bounds__(256, 2) void out_gemm(
    const u16* __restrict__ A, const u16* __restrict__ W,
    const float* __restrict__ bias, float* __restrict__ out) {
  const int flat = blockIdx.x;
  const int xcd = flat & 7, t = flat >> 3;
  const int n = t & 15, m = xcd * 4 + (t >> 4);
  gemm_core32<false, 1>(A, W, bias, out, false, m * 128, n * 64);
}

// ---------------- flash attention, S^T orientation, no running max ------------
// R6 version: global_load_lds staging + T5 setprio around MFMA clusters.
__global__ __launch_bounds__(256, 4) void attn_kernel(
    const u16* __restrict__ Qb, const u16* __restrict__ Kb, const u16* __restrict__ Vtb,
    const float* __restrict__ biasf, u16* __restrict__ Ob) {
  __shared__ u16 lK[128 * 64];
  __shared__ u16 lV[64 * 128];  // Vt2 slab, identity layout
  u16* lQ = lV;                 // prologue-only alias

  const int tid = threadIdx.x;
  const int lane = tid & 63, w = tid >> 6;
  const int quad = lane >> 4, l16 = lane & 15;
  const int rg = lane >> 3, cs = lane & 7;

  const int flat = blockIdx.x;
  const int xcd = flat & 7, r = flat >> 3;
  const int bh = xcd * 8 + (r & 7), qt = r >> 3;
  const int b = bh >> 4;
  const size_t qkBase = (size_t)b * 1048576 + (size_t)(bh & 15) * 64;
  const size_t vBase = (size_t)bh * 65536;
  const float C = 0.0450842200277982f;  // (1/sqrt(E)) * log2(e)
  const float* bp = biasf + b * 1024 + quad * 4;

#pragma unroll
  for (int t = 0; t < 2; ++t) {
    const int row = w * 16 + t * 8 + rg;
    const int c = cs ^ (row & 7);
    async_copy16(Qb + qkBase + (size_t)(qt * 64 + row) * 1024 + c * 8,
                 &lQ[(w * 16 + t * 8) * 64]);
  }
  __syncthreads();

  bf16x8 qf[2];
#pragma unroll
  for (int kk = 0; kk < 2; ++kk) {
    const int row = w * 16 + l16;
    qf[kk] = *(const bf16x8*)&lQ[row * 64 + (((kk * 4 + quad) ^ (row & 7)) * 8)];
  }
  __syncthreads();  // protect lQ before lV staging overwrites it

  float lsum = 0.f;
  f32x4 oacc[4];
#pragma unroll
  for (int dt = 0; dt < 4; ++dt) oacc[dt] = zero4();

  for (int it = 0; it < 8; ++it) {
    const int k0 = it * 128;
#pragma unroll
    for (int t = 0; t < 4; ++t) {
      const int row = w * 32 + t * 8 + rg;
      const int c = cs ^ (row & 7);
      async_copy16(Kb + qkBase + (size_t)(k0 + row) * 1024 + c * 8,
                   &lK[(w * 32 + t * 8) * 64]);
    }
#pragma unroll
    for (int t = 0; t < 4; ++t) {
      const int o16 = (w * 4 + t) * 512 + lane * 8;
      async_copy16(Vtb + vBase + (size_t)it * 8192 + o16, &lV[(w * 4 + t) * 512]);
    }
    __syncthreads();

    f32x4 sacc[8];
#pragma unroll
    for (int n = 0; n < 8; ++n) sacc[n] = zero4();
    __builtin_amdgcn_s_setprio(1);
#pragma unroll
    for (int kk = 0; kk < 2; ++kk) {
#pragma unroll
      for (int n = 0; n < 8; ++n) {
        const int row = n * 16 + l16;
        bf16x8 kf = *(const bf16x8*)&lK[row * 64 + (((kk * 4 + quad) ^ (row & 7)) * 8)];
        sacc[n] = __builtin_amdgcn_mfma_f32_16x16x32_bf16(kf, qf[kk], sacc[n], 0, 0, 0);
      }
    }
    __builtin_amdgcn_s_setprio(0);

    f32x4 sum4 = zero4();
#pragma unroll
    for (int n = 0; n < 8; ++n) {
      const float4 vb = *(const float4*)&bp[k0 + n * 16];
      sacc[n][0] = __builtin_amdgcn_exp2f(fmaf(sacc[n][0], C, vb.x));
      sacc[n][1] = __builtin_amdgcn_exp2f(fmaf(sacc[n][1], C, vb.y));
      sacc[n][2] = __builtin_amdgcn_exp2f(fmaf(sacc[n][2], C, vb.z));
      sacc[n][3] = __builtin_amdgcn_exp2f(fmaf(sacc[n][3], C, vb.w));
      sum4[0] += sacc[n][0]; sum4[1] += sacc[n][1];
      sum4[2] += sacc[n][2]; sum4[3] += sacc[n][3];
    }
    float rs = (sum4[0] + sum4[1]) + (sum4[2] + sum4[3]);
    rs += __shfl_xor(rs, 16);
    rs += __shfl_xor(rs, 32);
    lsum += rs;

    s16x4 pf[8];
#pragma unroll
    for (int n = 0; n < 8; ++n) {
      union { s16x4 v; unsigned int u[2]; } pu;
      pu.u[0] = pack2bf(sacc[n][0], sacc[n][1]);
      pu.u[1] = pack2bf(sacc[n][2], sacc[n][3]);
      pf[n] = pu.v;
    }

    __builtin_amdgcn_s_setprio(1);
#pragma unroll
    for (int dt = 0; dt < 4; ++dt) {
      const int dbase = (dt * 16 + l16) * 4;
#pragma unroll
      for (int ks = 0; ks < 8; ++ks) {
        s16x4 vf = *(const s16x4*)&lV[(ks * 4 + quad) * 256 + dbase];
        oacc[dt] = __builtin_amdgcn_mfma_f32_16x16x16bf16_1k(vf, pf[ks], oacc[dt], 0, 0, 0);
      }
    }
    __builtin_amdgcn_s_setprio(0);
    __syncthreads();
  }

  const float inv = 1.f / lsum;
  const int qg = qt * 64 + w * 16 + l16;
#pragma unroll
  for (int dt = 0; dt < 4; ++dt) {
    union { us4_t s; unsigned int u[2]; } pk;
    pk.u[0] = pack2bf(oacc[dt][0] * inv, oacc[dt][1] * inv);
    pk.u[1] = pack2bf(oacc[dt][2] * inv, oacc[dt][3] * inv);
    *(us4_t*)&Ob[qkBase + (size_t)qg * 1024 + dt * 16 + quad * 4] = pk.s;
  }
}

extern "C" void kernel_launch(void* const* d_in, const int* in_sizes, int n_in,
                              void* d_out, int out_size, void* d_ws, size_t ws_size,
                              hipStream_t stream) {
  const float* value  = (const float*)d_in[0];
  const float* key_in = (const float*)d_in[1];
  const float* query  = (const float*)d_in[2];
  const int*   mask   = (const int*)d_in[3];
  const float* Wq = (const float*)d_in[4];
  const float* bq = (const float*)d_in[5];
  const float* Wk = (const float*)d_in[6];
  const float* bk = (const float*)d_in[7];
  const float* Wv = (const float*)d_in[8];
  const float* bv = (const float*)d_in[9];
  const float* Wo = (const float*)d_in[10];
  const float* bo = (const float*)d_in[11];

  u16* ws = (u16*)d_ws;
  u16* q_bf  = ws;              // 4096x1024
  u16* k_bf  = ws + 4194304;
  u16* v_bf  = ws + 8388608;
  u16* wq_bf = ws + 12582912;   // 1024x1024 each
  u16* wk_bf = ws + 13631488;
  u16* wv_bf = ws + 14680064;
  u16* wo_bf = ws + 15728640;
  u16* Qbuf  = ws + 16777216;   // (b,s,h*64+d)
  u16* Kbuf  = ws + 20971520;
  u16* Vtbuf = ws + 25165824;   // Vt2[bh][s>>2][d][s&3]
  u16* attnb = ws + 29360128;   // (b,s,h*64+d)
  float* biasf = (float*)d_out; // consumed by attn, then overwritten by out_gemm

  fused_cast<<<16400, 256, 0, stream>>>(query, key_in, value, Wq, Wk, Wv, Wo, mask,
                                        q_bf, k_bf, v_bf, wq_bf, wk_bf, wv_bf, wo_bf,
                                        biasf);
  qkv_gemm256<<<dim3(192), 512, 0, stream>>>(q_bf, k_bf, v_bf, wq_bf, wk_bf, wv_bf,
                                             bq, bk, bv, Qbuf, Kbuf, Vtbuf);
  attn_kernel<<<dim3(1024), 256, 0, stream>>>(Qbuf, Kbuf, Vtbuf, biasf, attnb);
  out_gemm<<<dim3(512), 256, 0, stream>>>(attnb, wo_bf, bo, (float*)d_out);
}